// Round 3
// baseline (2125.193 us; speedup 1.0000x reference)
//
#include <hip/hip_runtime.h>
#include <stdint.h>

#define N_NODES 50000
#define N_EDGES 1600000
#define ETOT    (N_EDGES + N_NODES)
#define FN 16
#define FE 8
#define HID 64
#define NGR 8
#define NEG_ATT 0.2f
#define NEG_ACT 0.01f
#define EPS_BN 1e-5f
#define MEAN_BLOCKS 512
#define SELF_FLAG 0x40000000

typedef __attribute__((ext_vector_type(8))) short short8;
typedef __attribute__((ext_vector_type(4))) float f32x4;

__device__ __forceinline__ float bf2f(unsigned short u) {
  union { unsigned int i; float f; } c; c.i = ((unsigned int)u) << 16; return c.f;
}
__device__ __forceinline__ unsigned short f2bf(float f) {
  union { float f; unsigned int i; } c; c.f = f;
  unsigned int r = c.i + 0x7FFFu + ((c.i >> 16) & 1u);
  return (unsigned short)(r >> 16);
}
__device__ __forceinline__ float ubits(unsigned int u) {
  union { unsigned int i; float f; } c; c.i = u; return c.f;
}
__device__ __forceinline__ float lrelu(float x, float s) { return x > 0.f ? x : s * x; }

// ---------------- K1: xh = x @ node_W + node_b ----------------
__global__ __launch_bounds__(256) void k_node_embed(
    const float* __restrict__ x, const float* __restrict__ W,
    const float* __restrict__ b, float* __restrict__ xh) {
  __shared__ float sW[FN * HID];
  int t = threadIdx.x;
  for (int i = t; i < FN * HID; i += 256) sW[i] = W[i];
  __syncthreads();
  int j = t & 63;
  int v = blockIdx.x * 4 + (t >> 6);
  const float* xr = x + v * FN;
  float acc = b[j];
#pragma unroll
  for (int k = 0; k < FN; ++k) acc += xr[k] * sW[k * HID + j];
  xh[v * HID + j] = acc;
}

// ---------------- K2: in-degree histogram over dst ----------------
__global__ __launch_bounds__(256) void k_hist(const int* __restrict__ ei,
                                              int* __restrict__ counts) {
  int i = blockIdx.x * blockDim.x + threadIdx.x;
  int stride = gridDim.x * blockDim.x;
  for (; i < N_EDGES; i += stride) atomicAdd(&counts[ei[N_EDGES + i]], 1);
}

// ---------------- K3: exclusive scan -> row_ptr, fill ----------------
__global__ __launch_bounds__(1024) void k_scan(const int* __restrict__ counts,
                                               int* __restrict__ row_ptr,
                                               int* __restrict__ fill) {
  __shared__ int lds[1024];
  int t = threadIdx.x;
  const int CH = (N_NODES + 1023) / 1024;
  int lo = t * CH, hi = min(lo + CH, N_NODES);
  int s = 0;
  for (int v = lo; v < hi; ++v) s += counts[v] + 1;   // +1 self loop
  lds[t] = s; __syncthreads();
  for (int off = 1; off < 1024; off <<= 1) {
    int mine = lds[t];
    int add = (t >= off) ? lds[t - off] : 0;
    __syncthreads();
    lds[t] = mine + add;
    __syncthreads();
  }
  int run = (t > 0) ? lds[t - 1] : 0;
  for (int v = lo; v < hi; ++v) {
    row_ptr[v] = run; fill[v] = run;
    run += counts[v] + 1;
  }
  if (t == 1023) row_ptr[N_NODES] = lds[1023];
}

// ------- K4: scatter edges: src(+self flag) and bf16 edge_attr, dst-sorted -------
__global__ __launch_bounds__(256) void k_scatter(const int* __restrict__ ei,
                                                 const float* __restrict__ eattr,
                                                 int* __restrict__ fill,
                                                 int* __restrict__ src_sorted,
                                                 unsigned short* __restrict__ attr_s) {
  int i = blockIdx.x * blockDim.x + threadIdx.x;
  int stride = gridDim.x * blockDim.x;
  for (; i < ETOT; i += stride) {
    if (i < N_EDGES) {
      int d = ei[N_EDGES + i];
      int pos = atomicAdd(&fill[d], 1);
      src_sorted[pos] = ei[i];
      const float* ar = eattr + (size_t)i * FE;
      unsigned int w[4];
#pragma unroll
      for (int q = 0; q < 4; ++q)
        w[q] = (unsigned int)f2bf(ar[2 * q]) | ((unsigned int)f2bf(ar[2 * q + 1]) << 16);
      int4 pk = make_int4((int)w[0], (int)w[1], (int)w[2], (int)w[3]);
      *(int4*)(attr_s + (size_t)pos * FE) = pk;
    } else {
      int v = i - N_EDGES;
      int pos = atomicAdd(&fill[v], 1);
      src_sorted[pos] = v | SELF_FLAG;   // attr_s row left unwritten (never used)
    }
  }
}

// ------- K5: mean of ea over real edges (partials), then reduce -------
__global__ __launch_bounds__(256) void k_meanp(const float* __restrict__ eattr,
                                               const float* __restrict__ eW,
                                               const float* __restrict__ eb,
                                               float* __restrict__ partial) {
  __shared__ float sred[256];
  int t = threadIdx.x; int j = t & 63; int w = t >> 6;
  int wave = blockIdx.x * 4 + w;
  int nwaves = gridDim.x * 4;
  float Wj[8];
#pragma unroll
  for (int k = 0; k < 8; ++k) Wj[k] = eW[k * HID + j];
  float bj = eb[j], msum = 0.f;
  for (int i = wave; i < N_EDGES; i += nwaves) {
    const float4* ar = (const float4*)(eattr + (size_t)i * FE);
    float4 a0 = ar[0], a1 = ar[1];
    float acc = bj + a0.x * Wj[0] + a0.y * Wj[1] + a0.z * Wj[2] + a0.w * Wj[3]
                   + a1.x * Wj[4] + a1.y * Wj[5] + a1.z * Wj[6] + a1.w * Wj[7];
    msum += lrelu(acc, NEG_ACT);
  }
  sred[t] = msum; __syncthreads();
  if (w == 0)
    partial[blockIdx.x * HID + j] = sred[j] + sred[j + 64] + sred[j + 128] + sred[j + 192];
}

__global__ __launch_bounds__(256) void k_mean(const float* __restrict__ partial,
                                              float* __restrict__ mean) {
  __shared__ float sred[256];
  int t = threadIdx.x; int j = t & 63; int w = t >> 6;
  float s = 0.f;
  for (int bk = w; bk < MEAN_BLOCKS; bk += 4) s += partial[bk * HID + j];
  sred[t] = s; __syncthreads();
  if (w == 0)
    mean[j] = (sred[j] + sred[j + 64] + sred[j + 128] + sred[j + 192]) / (float)N_EDGES;
}

// ------- K6: e_self = mean(ea) @ Wed (fp32 exact) -------
__global__ void k_eself(const float* __restrict__ meanv,
                        const float* __restrict__ Wed,
                        float* __restrict__ e_self) {
  int j = threadIdx.x;
  float s = 0.f;
  for (int k = 0; k < HID; ++k) s += meanv[k] * Wed[k * HID + j];
  e_self[j] = s;
}

// ---------------- K7: xl = xh@Wl+bl, xr = xh@Wr+br ----------------
__global__ __launch_bounds__(256) void k_xlr(const float* __restrict__ xh,
                                             const float* __restrict__ Wl,
                                             const float* __restrict__ bl,
                                             const float* __restrict__ Wr,
                                             const float* __restrict__ br,
                                             float* __restrict__ xl,
                                             float* __restrict__ xr) {
  __shared__ float sWl[HID * HID], sWr[HID * HID];
  __shared__ float srow[4][HID];
  int t = threadIdx.x;
  for (int i = t; i < HID * HID; i += 256) { sWl[i] = Wl[i]; sWr[i] = Wr[i]; }
  __syncthreads();
  int j = t & 63; int w = t >> 6;
  int v = blockIdx.x * 4 + w;
  srow[w][j] = xh[v * HID + j];
  __syncthreads();
  float accL = bl[j], accR = br[j];
#pragma unroll
  for (int k = 0; k < HID; ++k) {
    float xk = srow[w][k];
    accL += xk * sWl[k * HID + j];
    accR += xk * sWr[k * HID + j];
  }
  xl[v * HID + j] = accL;
  xr[v * HID + j] = accR;
}

// ------- K8: fused ea-recompute + e = ea @ Wed (bf16 MFMA), per node-chunk -------
__global__ __launch_bounds__(256) void k_egemm(const unsigned short* __restrict__ attr_s,
                                               const float* __restrict__ eW,
                                               const float* __restrict__ eb,
                                               const float* __restrict__ Wed,
                                               const int* __restrict__ row_ptr,
                                               unsigned short* __restrict__ e_chunk,
                                               int v0, int v1) {
  int t = threadIdx.x;
  int lane = t & 63;
  int w = t >> 6;
  int wave = blockIdx.x * 4 + w;
  int nwaves = gridDim.x * 4;
  int l15 = lane & 15, lg = lane >> 4;

  // Per-lane eemb weights for this lane's 16 A-channels: {8lg..8lg+7} and {32+8lg..+7}
  float W0[8][8], W1[8][8], b0[8], b1[8];
#pragma unroll
  for (int i = 0; i < 8; ++i) { b0[i] = eb[8 * lg + i]; b1[i] = eb[32 + 8 * lg + i]; }
#pragma unroll
  for (int k = 0; k < 8; ++k)
#pragma unroll
    for (int i = 0; i < 8; ++i) {
      W0[k][i] = eW[k * HID + 8 * lg + i];
      W1[k][i] = eW[k * HID + 32 + 8 * lg + i];
    }

  // B-frags of Wed: B[k][col], col = lane&15, k = 8*(lane>>4)+i (+32 second half)
  short8 bfr[4][2];
#pragma unroll
  for (int jc = 0; jc < 4; ++jc)
#pragma unroll
    for (int kh = 0; kh < 2; ++kh)
#pragma unroll
      for (int i = 0; i < 8; ++i)
        bfr[jc][kh][i] = (short)f2bf(Wed[(8 * lg + i + 32 * kh) * HID + jc * 16 + l15]);

  int base = row_ptr[v0];
  int cnt = row_ptr[v1] - base;
  int ntiles = (cnt + 15) >> 4;
  for (int tile = wave; tile < ntiles; tile += nwaves) {
    int gidx = base + tile * 16 + l15;
    if (gidx > ETOT - 1) gidx = ETOT - 1;  // tail clamp (rows >= cnt never read)
    int4 araw = *(const int4*)(attr_s + (size_t)gidx * FE);
    float af[8];
#pragma unroll
    for (int q = 0; q < 4; ++q) {
      unsigned int u = (unsigned int)((&araw.x)[q]);
      af[2 * q]     = ubits(u << 16);
      af[2 * q + 1] = ubits(u & 0xFFFF0000u);
    }
    float e0[8], e1[8];
#pragma unroll
    for (int i = 0; i < 8; ++i) { e0[i] = b0[i]; e1[i] = b1[i]; }
#pragma unroll
    for (int k = 0; k < 8; ++k) {
      float ak = af[k];
#pragma unroll
      for (int i = 0; i < 8; ++i) { e0[i] += ak * W0[k][i]; e1[i] += ak * W1[k][i]; }
    }
    short8 a0, a1;
    unsigned int* a0u = (unsigned int*)&a0;
    unsigned int* a1u = (unsigned int*)&a1;
#pragma unroll
    for (int q = 0; q < 4; ++q) {
      float x0 = lrelu(e0[2 * q], NEG_ACT), x1 = lrelu(e0[2 * q + 1], NEG_ACT);
      asm("v_cvt_pk_bf16_f32 %0, %1, %2" : "=v"(a0u[q]) : "v"(x0), "v"(x1));
      float y0 = lrelu(e1[2 * q], NEG_ACT), y1 = lrelu(e1[2 * q + 1], NEG_ACT);
      asm("v_cvt_pk_bf16_f32 %0, %1, %2" : "=v"(a1u[q]) : "v"(y0), "v"(y1));
    }
    f32x4 acc[4] = {};
#pragma unroll
    for (int jc = 0; jc < 4; ++jc) {
      acc[jc] = __builtin_amdgcn_mfma_f32_16x16x32_bf16(a0, bfr[jc][0], acc[jc], 0, 0, 0);
      acc[jc] = __builtin_amdgcn_mfma_f32_16x16x32_bf16(a1, bfr[jc][1], acc[jc], 0, 0, 0);
    }
    unsigned short* ob = e_chunk + (size_t)tile * 16 * HID;
#pragma unroll
    for (int jc = 0; jc < 4; ++jc)
#pragma unroll
      for (int i = 0; i < 4; ++i)
        ob[(4 * lg + i) * HID + jc * 16 + l15] = f2bf(acc[jc][i]);  // D: col=l15, row=4lg+i
  }
}

// ------- K9: attention + online segment softmax (wave per node), per chunk -------
template <int HW>
__global__ __launch_bounds__(256) void k_attn(const float* __restrict__ xl,
                                              const float* __restrict__ xr,
                                              const unsigned short* __restrict__ e_chunk,
                                              const float* __restrict__ e_self,
                                              const int* __restrict__ row_ptr,
                                              const int* __restrict__ src_sorted,
                                              const float* __restrict__ att,
                                              const float* __restrict__ cb,
                                              float* __restrict__ xo,
                                              int v0, int v1) {
  int t = threadIdx.x;
  int j = t & 63;
  int v = v0 + blockIdx.x * 4 + (t >> 6);
  if (v >= v1) return;
  int base = row_ptr[v0];
  float xrv = xr[v * HID + j];
  float aj = att[j];
  float esj = e_self[j];
  int beg = row_ptr[v], end = row_ptr[v + 1];
  float M = -3.0e38f, S = 0.f, acc = 0.f;
  for (int i = beg; i < end; ++i) {
    int raw = src_sorted[i];
    int s = raw & 0x3FFFFFFF;
    float xls = xl[s * HID + j];
    float e = (raw & SELF_FLAG) ? esj : bf2f(e_chunk[(size_t)(i - base) * HID + j]);
    float m = lrelu(xls + xrv + e, NEG_ATT);
    float r = m * aj;
#pragma unroll
    for (int o = 1; o < HW; o <<= 1) r += __shfl_xor(r, o, 64);
    float Mn = fmaxf(M, r);
    float sc = __expf(M - Mn);
    float wgt = __expf(r - Mn);
    acc = acc * sc + wgt * xls;
    S = S * sc + wgt;
    M = Mn;
  }
  xo[v * HID + j] = acc / S + cb[j];
}

// ---------------- K10: BN stats ----------------
__global__ __launch_bounds__(256) void k_bnstats(const float* __restrict__ xo,
                                                 float* __restrict__ bns) {
  __shared__ float s1[256], s2[256];
  int t = threadIdx.x; int j = t & 63; int r = t >> 6;
  float sum = 0.f, sq = 0.f;
  int stride = gridDim.x * 4;
  for (int v = blockIdx.x * 4 + r; v < N_NODES; v += stride) {
    float x = xo[v * HID + j];
    sum += x; sq += x * x;
  }
  s1[t] = sum; s2[t] = sq; __syncthreads();
  if (r == 0) {
    atomicAdd(&bns[j], s1[j] + s1[j + 64] + s1[j + 128] + s1[j + 192]);
    atomicAdd(&bns[64 + j], s2[j] + s2[j + 64] + s2[j + 128] + s2[j + 192]);
  }
}

// ---------------- K11: BN apply + LeakyReLU -> xh ----------------
__global__ __launch_bounds__(256) void k_bnapply(const float* __restrict__ xo,
                                                 const float* __restrict__ bns,
                                                 const float* __restrict__ g,
                                                 const float* __restrict__ b,
                                                 float* __restrict__ xh) {
  int tid = blockIdx.x * 256 + threadIdx.x;
  int j = tid & 63;
  int v = tid >> 6;
  if (v >= N_NODES) return;
  const float invN = 1.f / (float)N_NODES;
  float mu = bns[j] * invN;
  float var = bns[64 + j] * invN - mu * mu;
  var = fmaxf(var, 0.f);
  float y = (xo[v * HID + j] - mu) * rsqrtf(var + EPS_BN) * g[j] + b[j];
  xh[v * HID + j] = lrelu(y, NEG_ACT);
}

// ---------------- K12: global add pool ----------------
__global__ __launch_bounds__(256) void k_pool(const float* __restrict__ xh,
                                              const int* __restrict__ batch,
                                              float* __restrict__ pooled) {
  __shared__ float lacc[4][NGR][HID];
  int t = threadIdx.x; int j = t & 63; int r = t >> 6;
  float a[NGR];
#pragma unroll
  for (int gg = 0; gg < NGR; ++gg) a[gg] = 0.f;
  int stride = gridDim.x * 4;
  for (int v = blockIdx.x * 4 + r; v < N_NODES; v += stride) {
    int g = batch[v];
    float x = xh[v * HID + j];
#pragma unroll
    for (int gg = 0; gg < NGR; ++gg) a[gg] += (g == gg) ? x : 0.f;
  }
#pragma unroll
  for (int gg = 0; gg < NGR; ++gg) lacc[r][gg][j] = a[gg];
  __syncthreads();
  if (r == 0) {
#pragma unroll
    for (int gg = 0; gg < NGR; ++gg)
      atomicAdd(&pooled[gg * HID + j],
                lacc[0][gg][j] + lacc[1][gg][j] + lacc[2][gg][j] + lacc[3][gg][j]);
  }
}

// ---------------- K13: readout ----------------
__global__ __launch_bounds__(256) void k_readout(const float* __restrict__ pooled,
                                                 const float* __restrict__ W1,
                                                 const float* __restrict__ b1,
                                                 const float* __restrict__ W2,
                                                 const float* __restrict__ b2,
                                                 float* __restrict__ out) {
  __shared__ float hid[NGR][32];
  int t = threadIdx.x;
  int g = t >> 5, q = t & 31;
  float acc = b1[q];
  for (int k = 0; k < HID; ++k) acc += pooled[g * HID + k] * W1[k * 32 + q];
  hid[g][q] = lrelu(acc, NEG_ACT);
  __syncthreads();
  if (t < NGR) {
    float o = b2[0];
    for (int q2 = 0; q2 < 32; ++q2) o += hid[t][q2] * W2[q2];
    out[t] = o;
  }
}

extern "C" void kernel_launch(void* const* d_in, const int* in_sizes, int n_in,
                              void* d_out, int out_size, void* d_ws, size_t ws_size,
                              hipStream_t stream) {
  (void)in_sizes; (void)n_in; (void)out_size;
  const float* x      = (const float*)d_in[0];
  const int*   ei     = (const int*)d_in[1];
  const float* eattr  = (const float*)d_in[2];
  const int*   batch  = (const int*)d_in[3];
  const float* node_W = (const float*)d_in[4];
  const float* node_b = (const float*)d_in[5];
  const float* eemb_W = (const float*)d_in[6];
  const float* eemb_b = (const float*)d_in[7];
  const float* ro1_W  = (const float*)d_in[35];
  const float* ro1_b  = (const float*)d_in[36];
  const float* ro2_W  = (const float*)d_in[37];
  const float* ro2_b  = (const float*)d_in[38];
  float* out = (float*)d_out;

  char* p = (char*)d_ws;
  auto alloc = [&](size_t bytes) {
    char* r = p;
    p += (bytes + 255) & ~(size_t)255;
    return r;
  };
  // --- zero zone (single memset) ---
  int*   counts = (int*)alloc((size_t)N_NODES * 4);
  float* bns    = (float*)alloc(3 * 128 * 4);
  float* pooled = (float*)alloc(NGR * HID * 4);
  size_t zero_bytes = (size_t)(p - (char*)d_ws);
  // --- fixed buffers (written before read every call) ---
  int*   row_ptr   = (int*)alloc((size_t)(N_NODES + 1) * 4);
  int*   fill      = (int*)alloc((size_t)N_NODES * 4);
  int*   src_sorted= (int*)alloc((size_t)ETOT * 4);
  unsigned short* attr_s = (unsigned short*)alloc((size_t)ETOT * FE * 2);
  float* partial   = (float*)alloc((size_t)MEAN_BLOCKS * HID * 4);
  float* meanv     = (float*)alloc(HID * 4);
  float* e_self    = (float*)alloc(HID * 4);
  float* xh        = (float*)alloc((size_t)N_NODES * HID * 4);
  float* xl        = (float*)alloc((size_t)N_NODES * HID * 4);
  float* xr        = (float*)alloc((size_t)N_NODES * HID * 4);
  float* xo        = (float*)alloc((size_t)N_NODES * HID * 4);
  size_t fixed_bytes = (size_t)(p - (char*)d_ws);

  // --- adaptive e-chunk: smallest chunk count whose buffer fits ws ---
  const int cand[6] = {1, 2, 4, 8, 20, 40};
  int nch = 40;
  size_t capE = 0;
  for (int ci = 0; ci < 6; ++ci) {
    int c = cand[ci];
    size_t ce = (size_t)(ETOT / c) + (size_t)(ETOT / (c * 12)) + 4096;
    if (c == 1) ce = ETOT;
    ce = (ce + 15) & ~(size_t)15;
    if (fixed_bytes + ce * HID * 2 <= ws_size) { nch = c; capE = ce; break; }
  }
  if (capE == 0) {  // last resort: clamp to whatever fits
    size_t avail = ws_size > fixed_bytes ? (ws_size - fixed_bytes) / (HID * 2) : 16;
    capE = avail & ~(size_t)15;
    if (capE < 16) capE = 16;
    nch = 40;
  }
  unsigned short* e_chunk = (unsigned short*)alloc(capE * HID * 2);
  const int RNODES = N_NODES / nch;

  hipMemsetAsync(d_ws, 0, zero_bytes, stream);

  k_node_embed<<<N_NODES / 4, 256, 0, stream>>>(x, node_W, node_b, xh);
  k_hist<<<1024, 256, 0, stream>>>(ei, counts);
  k_scan<<<1, 1024, 0, stream>>>(counts, row_ptr, fill);
  k_scatter<<<1024, 256, 0, stream>>>(ei, eattr, fill, src_sorted, attr_s);
  k_meanp<<<MEAN_BLOCKS, 256, 0, stream>>>(eattr, eemb_W, eemb_b, partial);
  k_mean<<<1, 256, 0, stream>>>(partial, meanv);

  for (int L = 0; L < 3; ++L) {
    const float* Wl  = (const float*)d_in[8 + 9 * L + 0];
    const float* bl  = (const float*)d_in[8 + 9 * L + 1];
    const float* Wr  = (const float*)d_in[8 + 9 * L + 2];
    const float* br  = (const float*)d_in[8 + 9 * L + 3];
    const float* Wed = (const float*)d_in[8 + 9 * L + 4];
    const float* att = (const float*)d_in[8 + 9 * L + 5];
    const float* cb  = (const float*)d_in[8 + 9 * L + 6];
    const float* g   = (const float*)d_in[8 + 9 * L + 7];
    const float* bt  = (const float*)d_in[8 + 9 * L + 8];
    k_xlr<<<N_NODES / 4, 256, 0, stream>>>(xh, Wl, bl, Wr, br, xl, xr);
    k_eself<<<1, 64, 0, stream>>>(meanv, Wed, e_self);
    for (int c = 0; c < nch; ++c) {
      int v0 = c * RNODES, v1 = v0 + RNODES;
      k_egemm<<<512, 256, 0, stream>>>(attr_s, eemb_W, eemb_b, Wed, row_ptr, e_chunk, v0, v1);
      int ablocks = (RNODES + 3) / 4;
      if (L < 2)
        k_attn<16><<<ablocks, 256, 0, stream>>>(xl, xr, e_chunk, e_self, row_ptr,
                                                src_sorted, att, cb, xo, v0, v1);
      else
        k_attn<64><<<ablocks, 256, 0, stream>>>(xl, xr, e_chunk, e_self, row_ptr,
                                                src_sorted, att, cb, xo, v0, v1);
    }
    k_bnstats<<<256, 256, 0, stream>>>(xo, bns + L * 128);
    k_bnapply<<<N_NODES * HID / 256, 256, 0, stream>>>(xo, bns + L * 128, g, bt, xh);
  }

  k_pool<<<64, 256, 0, stream>>>(xh, batch, pooled);
  k_readout<<<1, 256, 0, stream>>>(pooled, ro1_W, ro1_b, ro2_W, ro2_b, out);
}

// Round 4
// 1790.862 us; speedup vs baseline: 1.1867x; 1.1867x over previous
//
#include <hip/hip_runtime.h>
#include <stdint.h>

#define N_NODES 50000
#define N_EDGES 1600000
#define ETOT    (N_EDGES + N_NODES)
#define FN 16
#define FE 8
#define HID 64
#define NGR 8
#define NEG_ATT 0.2f
#define NEG_ACT 0.01f
#define EPS_BN 1e-5f
#define MEAN_BLOCKS 512
#define SELF_FLAG 0x40000000

typedef __attribute__((ext_vector_type(8))) short short8;
typedef __attribute__((ext_vector_type(4))) float f32x4;

__device__ __forceinline__ float bf2f(unsigned short u) {
  union { unsigned int i; float f; } c; c.i = ((unsigned int)u) << 16; return c.f;
}
__device__ __forceinline__ unsigned short f2bf(float f) {
  union { float f; unsigned int i; } c; c.f = f;
  unsigned int r = c.i + 0x7FFFu + ((c.i >> 16) & 1u);
  return (unsigned short)(r >> 16);
}
__device__ __forceinline__ float ubits(unsigned int u) {
  union { unsigned int i; float f; } c; c.i = u; return c.f;
}
__device__ __forceinline__ float lrelu(float x, float s) { return x > 0.f ? x : s * x; }

// ---------------- K1: xh = x @ node_W + node_b ----------------
__global__ __launch_bounds__(256) void k_node_embed(
    const float* __restrict__ x, const float* __restrict__ W,
    const float* __restrict__ b, float* __restrict__ xh) {
  __shared__ float sW[FN * HID];
  int t = threadIdx.x;
  for (int i = t; i < FN * HID; i += 256) sW[i] = W[i];
  __syncthreads();
  int j = t & 63;
  int v = blockIdx.x * 4 + (t >> 6);
  const float* xr = x + v * FN;
  float acc = b[j];
#pragma unroll
  for (int k = 0; k < FN; ++k) acc += xr[k] * sW[k * HID + j];
  xh[v * HID + j] = acc;
}

// ---------------- K2: in-degree histogram over dst ----------------
__global__ __launch_bounds__(256) void k_hist(const int* __restrict__ ei,
                                              int* __restrict__ counts) {
  int i = blockIdx.x * blockDim.x + threadIdx.x;
  int stride = gridDim.x * blockDim.x;
  for (; i < N_EDGES; i += stride) atomicAdd(&counts[ei[N_EDGES + i]], 1);
}

// ---------------- K3: exclusive scan -> row_ptr, fill ----------------
__global__ __launch_bounds__(1024) void k_scan(const int* __restrict__ counts,
                                               int* __restrict__ row_ptr,
                                               int* __restrict__ fill) {
  __shared__ int lds[1024];
  int t = threadIdx.x;
  const int CH = (N_NODES + 1023) / 1024;
  int lo = t * CH, hi = min(lo + CH, N_NODES);
  int s = 0;
  for (int v = lo; v < hi; ++v) s += counts[v] + 1;   // +1 self loop
  lds[t] = s; __syncthreads();
  for (int off = 1; off < 1024; off <<= 1) {
    int mine = lds[t];
    int add = (t >= off) ? lds[t - off] : 0;
    __syncthreads();
    lds[t] = mine + add;
    __syncthreads();
  }
  int run = (t > 0) ? lds[t - 1] : 0;
  for (int v = lo; v < hi; ++v) {
    row_ptr[v] = run; fill[v] = run;
    run += counts[v] + 1;
  }
  if (t == 1023) row_ptr[N_NODES] = lds[1023];
}

// ------- K4: scatter edges: src(+self flag) and bf16 edge_attr, dst-sorted -------
__global__ __launch_bounds__(256) void k_scatter(const int* __restrict__ ei,
                                                 const float* __restrict__ eattr,
                                                 int* __restrict__ fill,
                                                 int* __restrict__ src_sorted,
                                                 unsigned short* __restrict__ attr_s) {
  int i = blockIdx.x * blockDim.x + threadIdx.x;
  int stride = gridDim.x * blockDim.x;
  for (; i < ETOT; i += stride) {
    if (i < N_EDGES) {
      int d = ei[N_EDGES + i];
      int pos = atomicAdd(&fill[d], 1);
      src_sorted[pos] = ei[i];
      const float* ar = eattr + (size_t)i * FE;
      unsigned int w[4];
#pragma unroll
      for (int q = 0; q < 4; ++q)
        w[q] = (unsigned int)f2bf(ar[2 * q]) | ((unsigned int)f2bf(ar[2 * q + 1]) << 16);
      int4 pk = make_int4((int)w[0], (int)w[1], (int)w[2], (int)w[3]);
      *(int4*)(attr_s + (size_t)pos * FE) = pk;
    } else {
      int v = i - N_EDGES;
      int pos = atomicAdd(&fill[v], 1);
      src_sorted[pos] = v | SELF_FLAG;   // attr_s row left unwritten (never read)
    }
  }
}

// ------- K5: mean of ea over real edges — LDS-staged, coalesced -------
__global__ __launch_bounds__(256) void k_meanp(const float* __restrict__ eattr,
                                               const float* __restrict__ eW,
                                               const float* __restrict__ eb,
                                               float* __restrict__ partial) {
  __shared__ float sA[256 * FE];   // 8 KB: 256 edges x 8 attrs
  __shared__ float sred[256];
  int t = threadIdx.x; int j = t & 63; int w = t >> 6;
  float Wj[8];
#pragma unroll
  for (int k = 0; k < 8; ++k) Wj[k] = eW[k * HID + j];
  float bj = eb[j], msum = 0.f;
  const int TILES = N_EDGES / 256;   // 6250 exact
  for (int tile = blockIdx.x; tile < TILES; tile += gridDim.x) {
    __syncthreads();
    const float4* src = (const float4*)(eattr + (size_t)tile * 256 * FE);
    ((float4*)sA)[t] = src[t];
    ((float4*)sA)[t + 256] = src[t + 256];
    __syncthreads();
#pragma unroll 8
    for (int e = 0; e < 64; ++e) {
      const float4* ar = (const float4*)(sA + (w * 64 + e) * FE);  // wave-broadcast
      float4 A0 = ar[0], A1 = ar[1];
      float acc = bj + A0.x * Wj[0] + A0.y * Wj[1] + A0.z * Wj[2] + A0.w * Wj[3]
                     + A1.x * Wj[4] + A1.y * Wj[5] + A1.z * Wj[6] + A1.w * Wj[7];
      msum += lrelu(acc, NEG_ACT);
    }
  }
  sred[t] = msum; __syncthreads();
  if (w == 0)
    partial[blockIdx.x * HID + j] = sred[j] + sred[j + 64] + sred[j + 128] + sred[j + 192];
}

__global__ __launch_bounds__(256) void k_mean(const float* __restrict__ partial,
                                              float* __restrict__ mean) {
  __shared__ float sred[256];
  int t = threadIdx.x; int j = t & 63; int w = t >> 6;
  float s = 0.f;
  for (int bk = w; bk < MEAN_BLOCKS; bk += 4) s += partial[bk * HID + j];
  sred[t] = s; __syncthreads();
  if (w == 0)
    mean[j] = (sred[j] + sred[j + 64] + sred[j + 128] + sred[j + 192]) / (float)N_EDGES;
}

// ------- K6: e_self = mean(ea) @ Wed (fp32 exact) -------
__global__ void k_eself(const float* __restrict__ meanv,
                        const float* __restrict__ Wed,
                        float* __restrict__ e_self) {
  int j = threadIdx.x;
  float s = 0.f;
  for (int k = 0; k < HID; ++k) s += meanv[k] * Wed[k * HID + j];
  e_self[j] = s;
}

// ---------------- K7: xl = xh@Wl+bl, xr = xh@Wr+br ----------------
__global__ __launch_bounds__(256) void k_xlr(const float* __restrict__ xh,
                                             const float* __restrict__ Wl,
                                             const float* __restrict__ bl,
                                             const float* __restrict__ Wr,
                                             const float* __restrict__ br,
                                             float* __restrict__ xl,
                                             float* __restrict__ xr) {
  __shared__ float sWl[HID * HID], sWr[HID * HID];
  __shared__ float srow[4][HID];
  int t = threadIdx.x;
  for (int i = t; i < HID * HID; i += 256) { sWl[i] = Wl[i]; sWr[i] = Wr[i]; }
  __syncthreads();
  int j = t & 63; int w = t >> 6;
  int v = blockIdx.x * 4 + w;
  srow[w][j] = xh[v * HID + j];
  __syncthreads();
  float accL = bl[j], accR = br[j];
#pragma unroll
  for (int k = 0; k < HID; ++k) {
    float xk = srow[w][k];
    accL += xk * sWl[k * HID + j];
    accR += xk * sWr[k * HID + j];
  }
  xl[v * HID + j] = accL;
  xr[v * HID + j] = accR;
}

// ------- K8: fused ea-recompute + e = ea @ Wed (bf16 MFMA), per node-chunk -------
__global__ __launch_bounds__(256) void k_egemm(const unsigned short* __restrict__ attr_s,
                                               const float* __restrict__ eW,
                                               const float* __restrict__ eb,
                                               const float* __restrict__ Wed,
                                               const int* __restrict__ row_ptr,
                                               unsigned short* __restrict__ e_chunk,
                                               int v0, int v1, int capTiles) {
  __shared__ unsigned short sWed[HID * HID];  // 8 KB bf16
  __shared__ float seW[FE * HID];             // 2 KB
  __shared__ float seb[HID];
  int t = threadIdx.x;
  for (int i = t; i < HID * HID; i += 256) sWed[i] = f2bf(Wed[i]);
  for (int i = t; i < FE * HID; i += 256) seW[i] = eW[i];
  if (t < HID) seb[t] = eb[t];
  __syncthreads();

  int lane = t & 63;
  int w = t >> 6;
  int wave = blockIdx.x * 4 + w;
  int nwaves = gridDim.x * 4;
  int l15 = lane & 15, lg = lane >> 4;

  // Per-lane eemb weights for this lane's 16 A-channels: {8lg..+7} and {32+8lg..+7}
  float W0[8][8], W1[8][8], b0[8], b1[8];
#pragma unroll
  for (int i = 0; i < 8; ++i) { b0[i] = seb[8 * lg + i]; b1[i] = seb[32 + 8 * lg + i]; }
#pragma unroll
  for (int k = 0; k < 8; ++k) {
    *(float4*)&W0[k][0] = *(const float4*)&seW[k * HID + 8 * lg];
    *(float4*)&W0[k][4] = *(const float4*)&seW[k * HID + 8 * lg + 4];
    *(float4*)&W1[k][0] = *(const float4*)&seW[k * HID + 32 + 8 * lg];
    *(float4*)&W1[k][4] = *(const float4*)&seW[k * HID + 32 + 8 * lg + 4];
  }

  // B-frags of Wed: B[k][col], col = lane&15, k = 8*(lane>>4)+i (+32 second half)
  short8 bfr[4][2];
#pragma unroll
  for (int jc = 0; jc < 4; ++jc)
#pragma unroll
    for (int kh = 0; kh < 2; ++kh)
#pragma unroll
      for (int i = 0; i < 8; ++i)
        bfr[jc][kh][i] = (short)sWed[(8 * lg + i + 32 * kh) * HID + jc * 16 + l15];

  int base = row_ptr[v0];
  int cnt = row_ptr[v1] - base;
  int ntiles = (cnt + 15) >> 4;
  if (ntiles > capTiles) ntiles = capTiles;  // defensive (never expected)
  for (int tile = wave; tile < ntiles; tile += nwaves) {
    int gidx = base + tile * 16 + l15;
    if (gidx > ETOT - 1) gidx = ETOT - 1;  // tail clamp (rows >= cnt never read)
    int4 araw = *(const int4*)(attr_s + (size_t)gidx * FE);
    float af[8];
#pragma unroll
    for (int q = 0; q < 4; ++q) {
      unsigned int u = (unsigned int)((&araw.x)[q]);
      af[2 * q]     = ubits(u << 16);
      af[2 * q + 1] = ubits(u & 0xFFFF0000u);
    }
    float e0[8], e1[8];
#pragma unroll
    for (int i = 0; i < 8; ++i) { e0[i] = b0[i]; e1[i] = b1[i]; }
#pragma unroll
    for (int k = 0; k < 8; ++k) {
      float ak = af[k];
#pragma unroll
      for (int i = 0; i < 8; ++i) { e0[i] += ak * W0[k][i]; e1[i] += ak * W1[k][i]; }
    }
    short8 a0, a1;
    unsigned int* a0u = (unsigned int*)&a0;
    unsigned int* a1u = (unsigned int*)&a1;
#pragma unroll
    for (int q = 0; q < 4; ++q) {
      float x0 = lrelu(e0[2 * q], NEG_ACT), x1 = lrelu(e0[2 * q + 1], NEG_ACT);
      asm("v_cvt_pk_bf16_f32 %0, %1, %2" : "=v"(a0u[q]) : "v"(x0), "v"(x1));
      float y0 = lrelu(e1[2 * q], NEG_ACT), y1 = lrelu(e1[2 * q + 1], NEG_ACT);
      asm("v_cvt_pk_bf16_f32 %0, %1, %2" : "=v"(a1u[q]) : "v"(y0), "v"(y1));
    }
    f32x4 acc[4] = {};
#pragma unroll
    for (int jc = 0; jc < 4; ++jc) {
      acc[jc] = __builtin_amdgcn_mfma_f32_16x16x32_bf16(a0, bfr[jc][0], acc[jc], 0, 0, 0);
      acc[jc] = __builtin_amdgcn_mfma_f32_16x16x32_bf16(a1, bfr[jc][1], acc[jc], 0, 0, 0);
    }
    unsigned short* ob = e_chunk + (size_t)tile * 16 * HID;
#pragma unroll
    for (int jc = 0; jc < 4; ++jc)
#pragma unroll
      for (int i = 0; i < 4; ++i)
        ob[(4 * lg + i) * HID + jc * 16 + l15] = f2bf(acc[jc][i]);  // D: col=l15, row=4lg+i
  }
}

// ------- K9: attention + online segment softmax (wave per node), pairwise -------
template <int HW>
__global__ __launch_bounds__(256) void k_attn(const float* __restrict__ xl,
                                              const float* __restrict__ xr,
                                              const unsigned short* __restrict__ e_chunk,
                                              const float* __restrict__ e_self,
                                              const int* __restrict__ row_ptr,
                                              const int* __restrict__ src_sorted,
                                              const float* __restrict__ att,
                                              const float* __restrict__ cb,
                                              float* __restrict__ xo,
                                              int v0, int v1) {
  int t = threadIdx.x;
  int j = t & 63;
  int v = v0 + blockIdx.x * 4 + (t >> 6);
  if (v >= v1) return;
  int base = row_ptr[v0];
  float xrv = xr[v * HID + j];
  float aj = att[j];
  float esj = e_self[j];
  int beg = row_ptr[v], end = row_ptr[v + 1];
  float M = -3.0e38f, S = 0.f, acc = 0.f;
  int i = beg;
  if ((end - beg) & 1) {
    int raw = src_sorted[i];
    int s = raw & 0x3FFFFFFF;
    float xls = xl[s * HID + j];
    float e = (raw & SELF_FLAG) ? esj : bf2f(e_chunk[(size_t)(i - base) * HID + j]);
    float r = lrelu(xls + xrv + e, NEG_ATT) * aj;
#pragma unroll
    for (int o = 1; o < HW; o <<= 1) r += __shfl_xor(r, o, 64);
    M = r; S = 1.f; acc = xls;
    ++i;
  }
  for (; i < end; i += 2) {
    int raw0 = src_sorted[i], raw1 = src_sorted[i + 1];
    int s0 = raw0 & 0x3FFFFFFF, s1 = raw1 & 0x3FFFFFFF;
    float xls0 = xl[s0 * HID + j], xls1 = xl[s1 * HID + j];
    float e0 = (raw0 & SELF_FLAG) ? esj : bf2f(e_chunk[(size_t)(i - base) * HID + j]);
    float e1 = (raw1 & SELF_FLAG) ? esj : bf2f(e_chunk[(size_t)(i + 1 - base) * HID + j]);
    float r0 = lrelu(xls0 + xrv + e0, NEG_ATT) * aj;
    float r1 = lrelu(xls1 + xrv + e1, NEG_ATT) * aj;
#pragma unroll
    for (int o = 1; o < HW; o <<= 1) {
      r0 += __shfl_xor(r0, o, 64);
      r1 += __shfl_xor(r1, o, 64);
    }
    float Mn = fmaxf(M, fmaxf(r0, r1));
    float sc = __expf(M - Mn);
    float w0 = __expf(r0 - Mn);
    float w1 = __expf(r1 - Mn);
    acc = acc * sc + w0 * xls0 + w1 * xls1;
    S = S * sc + w0 + w1;
    M = Mn;
  }
  xo[v * HID + j] = acc / S + cb[j];
}

// ---------------- K10: BN stats ----------------
__global__ __launch_bounds__(256) void k_bnstats(const float* __restrict__ xo,
                                                 float* __restrict__ bns) {
  __shared__ float s1[256], s2[256];
  int t = threadIdx.x; int j = t & 63; int r = t >> 6;
  float sum = 0.f, sq = 0.f;
  int stride = gridDim.x * 4;
  for (int v = blockIdx.x * 4 + r; v < N_NODES; v += stride) {
    float x = xo[v * HID + j];
    sum += x; sq += x * x;
  }
  s1[t] = sum; s2[t] = sq; __syncthreads();
  if (r == 0) {
    atomicAdd(&bns[j], s1[j] + s1[j + 64] + s1[j + 128] + s1[j + 192]);
    atomicAdd(&bns[64 + j], s2[j] + s2[j + 64] + s2[j + 128] + s2[j + 192]);
  }
}

// ---------------- K11: BN apply + LeakyReLU -> xh ----------------
__global__ __launch_bounds__(256) void k_bnapply(const float* __restrict__ xo,
                                                 const float* __restrict__ bns,
                                                 const float* __restrict__ g,
                                                 const float* __restrict__ b,
                                                 float* __restrict__ xh) {
  int tid = blockIdx.x * 256 + threadIdx.x;
  int j = tid & 63;
  int v = tid >> 6;
  if (v >= N_NODES) return;
  const float invN = 1.f / (float)N_NODES;
  float mu = bns[j] * invN;
  float var = bns[64 + j] * invN - mu * mu;
  var = fmaxf(var, 0.f);
  float y = (xo[v * HID + j] - mu) * rsqrtf(var + EPS_BN) * g[j] + b[j];
  xh[v * HID + j] = lrelu(y, NEG_ACT);
}

// ---------------- K12: global add pool ----------------
__global__ __launch_bounds__(256) void k_pool(const float* __restrict__ xh,
                                              const int* __restrict__ batch,
                                              float* __restrict__ pooled) {
  __shared__ float lacc[4][NGR][HID];
  int t = threadIdx.x; int j = t & 63; int r = t >> 6;
  float a[NGR];
#pragma unroll
  for (int gg = 0; gg < NGR; ++gg) a[gg] = 0.f;
  int stride = gridDim.x * 4;
  for (int v = blockIdx.x * 4 + r; v < N_NODES; v += stride) {
    int g = batch[v];
    float x = xh[v * HID + j];
#pragma unroll
    for (int gg = 0; gg < NGR; ++gg) a[gg] += (g == gg) ? x : 0.f;
  }
#pragma unroll
  for (int gg = 0; gg < NGR; ++gg) lacc[r][gg][j] = a[gg];
  __syncthreads();
  if (r == 0) {
#pragma unroll
    for (int gg = 0; gg < NGR; ++gg)
      atomicAdd(&pooled[gg * HID + j],
                lacc[0][gg][j] + lacc[1][gg][j] + lacc[2][gg][j] + lacc[3][gg][j]);
  }
}

// ---------------- K13: readout ----------------
__global__ __launch_bounds__(256) void k_readout(const float* __restrict__ pooled,
                                                 const float* __restrict__ W1,
                                                 const float* __restrict__ b1,
                                                 const float* __restrict__ W2,
                                                 const float* __restrict__ b2,
                                                 float* __restrict__ out) {
  __shared__ float hid[NGR][32];
  int t = threadIdx.x;
  int g = t >> 5, q = t & 31;
  float acc = b1[q];
  for (int k = 0; k < HID; ++k) acc += pooled[g * HID + k] * W1[k * 32 + q];
  hid[g][q] = lrelu(acc, NEG_ACT);
  __syncthreads();
  if (t < NGR) {
    float o = b2[0];
    for (int q2 = 0; q2 < 32; ++q2) o += hid[t][q2] * W2[q2];
    out[t] = o;
  }
}

extern "C" void kernel_launch(void* const* d_in, const int* in_sizes, int n_in,
                              void* d_out, int out_size, void* d_ws, size_t ws_size,
                              hipStream_t stream) {
  (void)in_sizes; (void)n_in; (void)out_size;
  const float* x      = (const float*)d_in[0];
  const int*   ei     = (const int*)d_in[1];
  const float* eattr  = (const float*)d_in[2];
  const int*   batch  = (const int*)d_in[3];
  const float* node_W = (const float*)d_in[4];
  const float* node_b = (const float*)d_in[5];
  const float* eemb_W = (const float*)d_in[6];
  const float* eemb_b = (const float*)d_in[7];
  const float* ro1_W  = (const float*)d_in[35];
  const float* ro1_b  = (const float*)d_in[36];
  const float* ro2_W  = (const float*)d_in[37];
  const float* ro2_b  = (const float*)d_in[38];
  float* out = (float*)d_out;

  char* p = (char*)d_ws;
  auto alloc = [&](size_t bytes) {
    char* r = p;
    p += (bytes + 255) & ~(size_t)255;
    return r;
  };
  // --- zero zone (single memset) ---
  int*   counts = (int*)alloc((size_t)N_NODES * 4);
  float* bns    = (float*)alloc(3 * 128 * 4);
  float* pooled = (float*)alloc(NGR * HID * 4);
  size_t zero_bytes = (size_t)(p - (char*)d_ws);
  // --- fixed buffers (written before read every call) ---
  int*   row_ptr   = (int*)alloc((size_t)(N_NODES + 1) * 4);
  int*   fill      = (int*)alloc((size_t)N_NODES * 4);
  int*   src_sorted= (int*)alloc((size_t)ETOT * 4);
  unsigned short* attr_s = (unsigned short*)alloc((size_t)ETOT * FE * 2);
  float* partial   = (float*)alloc((size_t)MEAN_BLOCKS * HID * 4);
  float* meanv     = (float*)alloc(HID * 4);
  float* e_self    = (float*)alloc(HID * 4);
  float* xh        = (float*)alloc((size_t)N_NODES * HID * 4);
  float* xl        = (float*)alloc((size_t)N_NODES * HID * 4);
  float* xr        = (float*)alloc((size_t)N_NODES * HID * 4);
  float* xo        = (float*)alloc((size_t)N_NODES * HID * 4);
  size_t fixed_bytes = (size_t)(p - (char*)d_ws);

  // --- adaptive e-chunk: smallest chunk count whose buffer fits ws ---
  const int cand[15] = {1, 2, 3, 4, 5, 6, 8, 10, 13, 17, 20, 25, 34, 40, 50};
  int nch = 0;
  size_t capE = 0;
  for (int ci = 0; ci < 15; ++ci) {
    int c = cand[ci];
    int rn = (N_NODES + c - 1) / c;
    size_t exp_e = ((size_t)ETOT * rn) / N_NODES;
    size_t ce = (c == 1) ? (size_t)ETOT : (exp_e + exp_e / 8 + 8192);
    ce = (ce + 15) & ~(size_t)15;
    if (fixed_bytes + ce * HID * 2 <= ws_size) { nch = c; capE = ce; break; }
  }
  if (nch == 0) {  // last resort: clamp to whatever fits
    size_t avail = ws_size > fixed_bytes ? (ws_size - fixed_bytes) / (HID * 2) : 16;
    capE = avail & ~(size_t)15;
    if (capE < 16) capE = 16;
    nch = 50;
  }
  unsigned short* e_chunk = (unsigned short*)alloc(capE * HID * 2);
  const int RNODES = (N_NODES + nch - 1) / nch;
  const int capTiles = (int)(capE / 16);
  int egrid = (int)(capE / 256);          // ~tiles/16 -> ~4 tiles per wave
  if (egrid < 32) egrid = 32;
  if (egrid > 512) egrid = 512;

  hipMemsetAsync(d_ws, 0, zero_bytes, stream);

  k_node_embed<<<N_NODES / 4, 256, 0, stream>>>(x, node_W, node_b, xh);
  k_hist<<<1024, 256, 0, stream>>>(ei, counts);
  k_scan<<<1, 1024, 0, stream>>>(counts, row_ptr, fill);
  k_scatter<<<1024, 256, 0, stream>>>(ei, eattr, fill, src_sorted, attr_s);
  k_meanp<<<MEAN_BLOCKS, 256, 0, stream>>>(eattr, eemb_W, eemb_b, partial);
  k_mean<<<1, 256, 0, stream>>>(partial, meanv);

  for (int L = 0; L < 3; ++L) {
    const float* Wl  = (const float*)d_in[8 + 9 * L + 0];
    const float* bl  = (const float*)d_in[8 + 9 * L + 1];
    const float* Wr  = (const float*)d_in[8 + 9 * L + 2];
    const float* br  = (const float*)d_in[8 + 9 * L + 3];
    const float* Wed = (const float*)d_in[8 + 9 * L + 4];
    const float* att = (const float*)d_in[8 + 9 * L + 5];
    const float* cb  = (const float*)d_in[8 + 9 * L + 6];
    const float* g   = (const float*)d_in[8 + 9 * L + 7];
    const float* bt  = (const float*)d_in[8 + 9 * L + 8];
    k_xlr<<<N_NODES / 4, 256, 0, stream>>>(xh, Wl, bl, Wr, br, xl, xr);
    k_eself<<<1, 64, 0, stream>>>(meanv, Wed, e_self);
    for (int c = 0; c < nch; ++c) {
      int v0 = c * RNODES;
      int v1 = v0 + RNODES; if (v1 > N_NODES) v1 = N_NODES;
      if (v0 >= v1) break;
      k_egemm<<<egrid, 256, 0, stream>>>(attr_s, eemb_W, eemb_b, Wed, row_ptr,
                                         e_chunk, v0, v1, capTiles);
      int ablocks = (v1 - v0 + 3) / 4;
      if (L < 2)
        k_attn<16><<<ablocks, 256, 0, stream>>>(xl, xr, e_chunk, e_self, row_ptr,
                                                src_sorted, att, cb, xo, v0, v1);
      else
        k_attn<64><<<ablocks, 256, 0, stream>>>(xl, xr, e_chunk, e_self, row_ptr,
                                                src_sorted, att, cb, xo, v0, v1);
    }
    k_bnstats<<<256, 256, 0, stream>>>(xo, bns + L * 128);
    k_bnapply<<<N_NODES * HID / 256, 256, 0, stream>>>(xo, bns + L * 128, g, bt, xh);
  }

  k_pool<<<64, 256, 0, stream>>>(xh, batch, pooled);
  k_readout<<<1, 256, 0, stream>>>(pooled, ro1_W, ro1_b, ro2_W, ro2_b, out);
}

// Round 5
// 1689.735 us; speedup vs baseline: 1.2577x; 1.0598x over previous
//
#include <hip/hip_runtime.h>
#include <stdint.h>

#define N_NODES 50000
#define N_EDGES 1600000
#define ETOT    (N_EDGES + N_NODES)
#define FN 16
#define FE 8
#define HID 64
#define NGR 8
#define NEG_ATT 0.2f
#define NEG_ACT 0.01f
#define EPS_BN 1e-5f
#define MEAN_BLOCKS 512
#define SELF_FLAG 0x40000000
#define SRC_MASK  0x3FFFFFFF

typedef __attribute__((ext_vector_type(8))) short short8;
typedef __attribute__((ext_vector_type(4))) float f32x4;

__device__ __forceinline__ float bf2f(unsigned short u) {
  union { unsigned int i; float f; } c; c.i = ((unsigned int)u) << 16; return c.f;
}
__device__ __forceinline__ unsigned short f2bf(float f) {
  union { float f; unsigned int i; } c; c.f = f;
  unsigned int r = c.i + 0x7FFFu + ((c.i >> 16) & 1u);
  return (unsigned short)(r >> 16);
}
__device__ __forceinline__ float lrelu(float x, float s) { return x > 0.f ? x : s * x; }

// ---------------- K1: xh = x @ node_W + node_b ----------------
__global__ __launch_bounds__(256) void k_node_embed(
    const float* __restrict__ x, const float* __restrict__ W,
    const float* __restrict__ b, float* __restrict__ xh) {
  __shared__ float sW[FN * HID];
  int t = threadIdx.x;
  for (int i = t; i < FN * HID; i += 256) sW[i] = W[i];
  __syncthreads();
  int j = t & 63;
  int v = blockIdx.x * 4 + (t >> 6);
  const float* xr = x + v * FN;
  float acc = b[j];
#pragma unroll
  for (int k = 0; k < FN; ++k) acc += xr[k] * sW[k * HID + j];
  xh[v * HID + j] = acc;
}

// ---------------- K2: in-degree histogram over dst ----------------
__global__ __launch_bounds__(256) void k_hist(const int* __restrict__ ei,
                                              int* __restrict__ counts) {
  int i = blockIdx.x * blockDim.x + threadIdx.x;
  int stride = gridDim.x * blockDim.x;
  for (; i < N_EDGES; i += stride) atomicAdd(&counts[ei[N_EDGES + i]], 1);
}

// ---------------- K3: exclusive scan -> row_ptr, fill ----------------
__global__ __launch_bounds__(1024) void k_scan(const int* __restrict__ counts,
                                               int* __restrict__ row_ptr,
                                               int* __restrict__ fill) {
  __shared__ int lds[1024];
  int t = threadIdx.x;
  const int CH = (N_NODES + 1023) / 1024;
  int lo = t * CH, hi = min(lo + CH, N_NODES);
  int s = 0;
  for (int v = lo; v < hi; ++v) s += counts[v] + 1;   // +1 self loop
  lds[t] = s; __syncthreads();
  for (int off = 1; off < 1024; off <<= 1) {
    int mine = lds[t];
    int add = (t >= off) ? lds[t - off] : 0;
    __syncthreads();
    lds[t] = mine + add;
    __syncthreads();
  }
  int run = (t > 0) ? lds[t - 1] : 0;
  for (int v = lo; v < hi; ++v) {
    row_ptr[v] = run; fill[v] = run;
    run += counts[v] + 1;
  }
  if (t == 1023) row_ptr[N_NODES] = lds[1023];
}

// ------- K4: scatter (src|flag, perm) 8B records, dst-sorted -------
__global__ __launch_bounds__(256) void k_scatter(const int* __restrict__ ei,
                                                 int* __restrict__ fill,
                                                 int2* __restrict__ srcperm) {
  int i = blockIdx.x * blockDim.x + threadIdx.x;
  int stride = gridDim.x * blockDim.x;
  for (; i < ETOT; i += stride) {
    if (i < N_EDGES) {
      int d = ei[N_EDGES + i];
      int pos = atomicAdd(&fill[d], 1);
      srcperm[pos] = make_int2(ei[i], i);
    } else {
      int v = i - N_EDGES;
      int pos = atomicAdd(&fill[v], 1);
      srcperm[pos] = make_int2(v | SELF_FLAG, 0);
    }
  }
}

// ------- K4b: edge_attr fp32 -> bf16, original order (coalesced) -------
__global__ __launch_bounds__(256) void k_attr_cvt(const float* __restrict__ eattr,
                                                  unsigned short* __restrict__ attr_bf) {
  int idx = blockIdx.x * 256 + threadIdx.x;   // over N_EDGES*FE/4
  float4 a = ((const float4*)eattr)[idx];
  unsigned int lo = (unsigned int)f2bf(a.x) | ((unsigned int)f2bf(a.y) << 16);
  unsigned int hi = (unsigned int)f2bf(a.z) | ((unsigned int)f2bf(a.w) << 16);
  ((int2*)attr_bf)[idx] = make_int2((int)lo, (int)hi);
}

// ------- K5: mean of ea over real edges — LDS-staged, coalesced -------
__global__ __launch_bounds__(256) void k_meanp(const float* __restrict__ eattr,
                                               const float* __restrict__ eW,
                                               const float* __restrict__ eb,
                                               float* __restrict__ partial) {
  __shared__ float sA[256 * FE];
  __shared__ float sred[256];
  int t = threadIdx.x; int j = t & 63; int w = t >> 6;
  float Wj[8];
#pragma unroll
  for (int k = 0; k < 8; ++k) Wj[k] = eW[k * HID + j];
  float bj = eb[j], msum = 0.f;
  const int TILES = N_EDGES / 256;
  for (int tile = blockIdx.x; tile < TILES; tile += gridDim.x) {
    __syncthreads();
    const float4* src = (const float4*)(eattr + (size_t)tile * 256 * FE);
    ((float4*)sA)[t] = src[t];
    ((float4*)sA)[t + 256] = src[t + 256];
    __syncthreads();
#pragma unroll 8
    for (int e = 0; e < 64; ++e) {
      const float4* ar = (const float4*)(sA + (w * 64 + e) * FE);
      float4 A0 = ar[0], A1 = ar[1];
      float acc = bj + A0.x * Wj[0] + A0.y * Wj[1] + A0.z * Wj[2] + A0.w * Wj[3]
                     + A1.x * Wj[4] + A1.y * Wj[5] + A1.z * Wj[6] + A1.w * Wj[7];
      msum += lrelu(acc, NEG_ACT);
    }
  }
  sred[t] = msum; __syncthreads();
  if (w == 0)
    partial[blockIdx.x * HID + j] = sred[j] + sred[j + 64] + sred[j + 128] + sred[j + 192];
}

__global__ __launch_bounds__(256) void k_mean(const float* __restrict__ partial,
                                              float* __restrict__ mean) {
  __shared__ float sred[256];
  int t = threadIdx.x; int j = t & 63; int w = t >> 6;
  float s = 0.f;
  for (int bk = w; bk < MEAN_BLOCKS; bk += 4) s += partial[bk * HID + j];
  sred[t] = s; __syncthreads();
  if (w == 0)
    mean[j] = (sred[j] + sred[j + 64] + sred[j + 128] + sred[j + 192]) / (float)N_EDGES;
}

// ------- K6: e_self = mean(ea) @ Wed (fp32 exact) -------
__global__ void k_eself(const float* __restrict__ meanv,
                        const float* __restrict__ Wed,
                        float* __restrict__ e_self) {
  int j = threadIdx.x;
  float s = 0.f;
  for (int k = 0; k < HID; ++k) s += meanv[k] * Wed[k * HID + j];
  e_self[j] = s;
}

// ---------------- K7: xl = xh@Wl+bl, xr = xh@Wr+br ----------------
__global__ __launch_bounds__(256) void k_xlr(const float* __restrict__ xh,
                                             const float* __restrict__ Wl,
                                             const float* __restrict__ bl,
                                             const float* __restrict__ Wr,
                                             const float* __restrict__ br,
                                             float* __restrict__ xl,
                                             float* __restrict__ xr) {
  __shared__ float sWl[HID * HID], sWr[HID * HID];
  __shared__ float srow[4][HID];
  int t = threadIdx.x;
  for (int i = t; i < HID * HID; i += 256) { sWl[i] = Wl[i]; sWr[i] = Wr[i]; }
  __syncthreads();
  int j = t & 63; int w = t >> 6;
  int v = blockIdx.x * 4 + w;
  srow[w][j] = xh[v * HID + j];
  __syncthreads();
  float accL = bl[j], accR = br[j];
#pragma unroll
  for (int k = 0; k < HID; ++k) {
    float xk = srow[w][k];
    accL += xk * sWl[k * HID + j];
    accR += xk * sWr[k * HID + j];
  }
  xl[v * HID + j] = accL;
  xr[v * HID + j] = accR;
}

// ======= K8: FUSED attention: in-kernel e = lrelu(attr@eW+b)@Wed via 2 MFMAs
//         + LDS transpose + online segment softmax. Wave per node. =======
template <int HW>
__global__ __launch_bounds__(256) void k_attn_f(
    const float* __restrict__ xl, const float* __restrict__ xr,
    const unsigned short* __restrict__ attr_bf,
    const int2* __restrict__ srcperm, const int* __restrict__ row_ptr,
    const float* __restrict__ eW, const float* __restrict__ eb,
    const float* __restrict__ Wed, const float* __restrict__ e_self,
    const float* __restrict__ att, const float* __restrict__ cb,
    float* __restrict__ xo) {
  __shared__ unsigned short sWed[HID * HID];   // 8 KB bf16
  __shared__ unsigned short sEw[FE * HID];     // 1 KB bf16
  __shared__ float sEb[HID];
  __shared__ __align__(16) unsigned short T1[4][16][72];  // ea tiles (per wave)
  __shared__ float T2[4][16][66];                          // e tiles (per wave)

  int t = threadIdx.x;
  for (int i = t; i < HID * HID; i += 256) sWed[i] = f2bf(Wed[i]);
  for (int i = t; i < FE * HID; i += 256) sEw[i] = f2bf(eW[i]);
  if (t < HID) sEb[t] = eb[t];
  __syncthreads();

  int lane = t & 63, w = t >> 6, l15 = lane & 15, lg = lane >> 4;

  // Wed B-frags: B[k][col], col=l15(+16jc), k=8lg+i (+32 for kh=1)
  short8 bW[4][2];
#pragma unroll
  for (int jc = 0; jc < 4; ++jc)
#pragma unroll
    for (int kh = 0; kh < 2; ++kh)
#pragma unroll
      for (int i = 0; i < 8; ++i)
        bW[jc][kh][i] = (short)sWed[(8 * lg + i + 32 * kh) * HID + jc * 16 + l15];
  // eW B-frags (K padded 8->32: only lg==0 holds real k=0..7)
  short8 bE[4] = {};
  if (lg == 0)
#pragma unroll
    for (int jc = 0; jc < 4; ++jc)
#pragma unroll
      for (int i = 0; i < 8; ++i)
        bE[jc][i] = (short)sEw[i * HID + jc * 16 + l15];
  float biasv[4];
#pragma unroll
  for (int jc = 0; jc < 4; ++jc) biasv[jc] = sEb[jc * 16 + l15];

  int v = blockIdx.x * 4 + w;
  if (v >= N_NODES) return;

  float xrv = xr[v * HID + lane];
  float attj = att[lane];
  float esj = e_self[lane];
  float cbj = cb[lane];
  int beg = row_ptr[v], end = row_ptr[v + 1];
  float M = -3.0e38f, S = 0.f, acc = 0.f;

  for (int base = beg; base < end; base += 16) {
    int cnt = end - base; if (cnt > 16) cnt = 16;
    int eidx = base + l15; if (eidx >= end) eidx = end - 1;
    int2 sp = srcperm[eidx];
    // ---- MFMA1: ea = attr(16x8, K-pad 32) @ eW -> D[edge=4lg+i][ch=jc16+l15]
    short8 a0 = {};
    if (lg == 0 && !(sp.x & SELF_FLAG))
      a0 = *(const short8*)(attr_bf + (size_t)sp.y * FE);
    f32x4 accE[4];
#pragma unroll
    for (int jc = 0; jc < 4; ++jc) {
      f32x4 z = {};
      accE[jc] = __builtin_amdgcn_mfma_f32_16x16x32_bf16(a0, bE[jc], z, 0, 0, 0);
    }
    // bias + lrelu -> T1[edge][ch] (bf16)
#pragma unroll
    for (int jc = 0; jc < 4; ++jc)
#pragma unroll
      for (int i = 0; i < 4; ++i)
        T1[w][4 * lg + i][jc * 16 + l15] =
            f2bf(lrelu(accE[jc][i] + biasv[jc], NEG_ACT));
    __builtin_amdgcn_wave_barrier();
    asm volatile("s_waitcnt lgkmcnt(0)" ::: "memory");
    __builtin_amdgcn_sched_barrier(0);
    // ---- MFMA2: e = ea(16x64) @ Wed -> D[edge=4lg+i][ch=jc16+l15]
    short8 A0 = *(const short8*)&T1[w][l15][8 * lg];
    short8 A1 = *(const short8*)&T1[w][l15][32 + 8 * lg];
    f32x4 acc2[4];
#pragma unroll
    for (int jc = 0; jc < 4; ++jc) {
      f32x4 z = {};
      acc2[jc] = __builtin_amdgcn_mfma_f32_16x16x32_bf16(A0, bW[jc][0], z, 0, 0, 0);
      acc2[jc] = __builtin_amdgcn_mfma_f32_16x16x32_bf16(A1, bW[jc][1], acc2[jc], 0, 0, 0);
    }
#pragma unroll
    for (int jc = 0; jc < 4; ++jc)
#pragma unroll
      for (int i = 0; i < 4; ++i)
        T2[w][4 * lg + i][jc * 16 + l15] = acc2[jc][i];
    __builtin_amdgcn_wave_barrier();
    asm volatile("s_waitcnt lgkmcnt(0)" ::: "memory");
    __builtin_amdgcn_sched_barrier(0);
    // ---- online segment softmax over this tile's edges (pairwise)
    int ii = 0;
    if (cnt & 1) {
      int raw = __shfl(sp.x, 0, 64);
      float e = (raw & SELF_FLAG) ? esj : T2[w][0][lane];
      float xls = xl[(size_t)(raw & SRC_MASK) * HID + lane];
      float r = lrelu(xls + xrv + e, NEG_ATT) * attj;
#pragma unroll
      for (int o = 1; o < HW; o <<= 1) r += __shfl_xor(r, o, 64);
      float Mn = fmaxf(M, r);
      float sc = __expf(M - Mn), wt = __expf(r - Mn);
      acc = acc * sc + wt * xls;
      S = S * sc + wt; M = Mn;
      ii = 1;
    }
    for (; ii < cnt; ii += 2) {
      int raw0 = __shfl(sp.x, ii, 64), raw1 = __shfl(sp.x, ii + 1, 64);
      float e0 = (raw0 & SELF_FLAG) ? esj : T2[w][ii][lane];
      float e1 = (raw1 & SELF_FLAG) ? esj : T2[w][ii + 1][lane];
      float xls0 = xl[(size_t)(raw0 & SRC_MASK) * HID + lane];
      float xls1 = xl[(size_t)(raw1 & SRC_MASK) * HID + lane];
      float r0 = lrelu(xls0 + xrv + e0, NEG_ATT) * attj;
      float r1 = lrelu(xls1 + xrv + e1, NEG_ATT) * attj;
#pragma unroll
      for (int o = 1; o < HW; o <<= 1) {
        r0 += __shfl_xor(r0, o, 64);
        r1 += __shfl_xor(r1, o, 64);
      }
      float Mn = fmaxf(M, fmaxf(r0, r1));
      float sc = __expf(M - Mn);
      float w0 = __expf(r0 - Mn), w1 = __expf(r1 - Mn);
      acc = acc * sc + w0 * xls0 + w1 * xls1;
      S = S * sc + w0 + w1; M = Mn;
    }
    __builtin_amdgcn_wave_barrier();
  }
  xo[v * HID + lane] = acc / S + cbj;
}

// ---------------- K10: BN stats ----------------
__global__ __launch_bounds__(256) void k_bnstats(const float* __restrict__ xo,
                                                 float* __restrict__ bns) {
  __shared__ float s1[256], s2[256];
  int t = threadIdx.x; int j = t & 63; int r = t >> 6;
  float sum = 0.f, sq = 0.f;
  int stride = gridDim.x * 4;
  for (int v = blockIdx.x * 4 + r; v < N_NODES; v += stride) {
    float x = xo[v * HID + j];
    sum += x; sq += x * x;
  }
  s1[t] = sum; s2[t] = sq; __syncthreads();
  if (r == 0) {
    atomicAdd(&bns[j], s1[j] + s1[j + 64] + s1[j + 128] + s1[j + 192]);
    atomicAdd(&bns[64 + j], s2[j] + s2[j + 64] + s2[j + 128] + s2[j + 192]);
  }
}

// ---------------- K11: BN apply + LeakyReLU (in-place safe) ----------------
__global__ __launch_bounds__(256) void k_bnapply(const float* __restrict__ xo,
                                                 const float* __restrict__ bns,
                                                 const float* __restrict__ g,
                                                 const float* __restrict__ b,
                                                 float* __restrict__ xh) {
  int tid = blockIdx.x * 256 + threadIdx.x;
  int j = tid & 63;
  int v = tid >> 6;
  if (v >= N_NODES) return;
  const float invN = 1.f / (float)N_NODES;
  float mu = bns[j] * invN;
  float var = bns[64 + j] * invN - mu * mu;
  var = fmaxf(var, 0.f);
  float y = (xo[v * HID + j] - mu) * rsqrtf(var + EPS_BN) * g[j] + b[j];
  xh[v * HID + j] = lrelu(y, NEG_ACT);
}

// ---------------- K12: global add pool ----------------
__global__ __launch_bounds__(256) void k_pool(const float* __restrict__ xh,
                                              const int* __restrict__ batch,
                                              float* __restrict__ pooled) {
  __shared__ float lacc[4][NGR][HID];
  int t = threadIdx.x; int j = t & 63; int r = t >> 6;
  float a[NGR];
#pragma unroll
  for (int gg = 0; gg < NGR; ++gg) a[gg] = 0.f;
  int stride = gridDim.x * 4;
  for (int v = blockIdx.x * 4 + r; v < N_NODES; v += stride) {
    int g = batch[v];
    float x = xh[v * HID + j];
#pragma unroll
    for (int gg = 0; gg < NGR; ++gg) a[gg] += (g == gg) ? x : 0.f;
  }
#pragma unroll
  for (int gg = 0; gg < NGR; ++gg) lacc[r][gg][j] = a[gg];
  __syncthreads();
  if (r == 0) {
#pragma unroll
    for (int gg = 0; gg < NGR; ++gg)
      atomicAdd(&pooled[gg * HID + j],
                lacc[0][gg][j] + lacc[1][gg][j] + lacc[2][gg][j] + lacc[3][gg][j]);
  }
}

// ---------------- K13: readout ----------------
__global__ __launch_bounds__(256) void k_readout(const float* __restrict__ pooled,
                                                 const float* __restrict__ W1,
                                                 const float* __restrict__ b1,
                                                 const float* __restrict__ W2,
                                                 const float* __restrict__ b2,
                                                 float* __restrict__ out) {
  __shared__ float hid[NGR][32];
  int t = threadIdx.x;
  int g = t >> 5, q = t & 31;
  float acc = b1[q];
  for (int k = 0; k < HID; ++k) acc += pooled[g * HID + k] * W1[k * 32 + q];
  hid[g][q] = lrelu(acc, NEG_ACT);
  __syncthreads();
  if (t < NGR) {
    float o = b2[0];
    for (int q2 = 0; q2 < 32; ++q2) o += hid[t][q2] * W2[q2];
    out[t] = o;
  }
}

extern "C" void kernel_launch(void* const* d_in, const int* in_sizes, int n_in,
                              void* d_out, int out_size, void* d_ws, size_t ws_size,
                              hipStream_t stream) {
  (void)in_sizes; (void)n_in; (void)out_size; (void)ws_size;
  const float* x      = (const float*)d_in[0];
  const int*   ei     = (const int*)d_in[1];
  const float* eattr  = (const float*)d_in[2];
  const int*   batch  = (const int*)d_in[3];
  const float* node_W = (const float*)d_in[4];
  const float* node_b = (const float*)d_in[5];
  const float* eemb_W = (const float*)d_in[6];
  const float* eemb_b = (const float*)d_in[7];
  const float* ro1_W  = (const float*)d_in[35];
  const float* ro1_b  = (const float*)d_in[36];
  const float* ro2_W  = (const float*)d_in[37];
  const float* ro2_b  = (const float*)d_in[38];
  float* out = (float*)d_out;

  char* p = (char*)d_ws;
  auto alloc = [&](size_t bytes) {
    char* r = p;
    p += (bytes + 255) & ~(size_t)255;
    return r;
  };
  // --- zero zone (single memset) ---
  int*   counts = (int*)alloc((size_t)N_NODES * 4);
  float* bns    = (float*)alloc(3 * 128 * 4);
  float* pooled = (float*)alloc(NGR * HID * 4);
  size_t zero_bytes = (size_t)(p - (char*)d_ws);
  // --- fixed buffers (each written before read every call) ---
  int*   row_ptr = (int*)alloc((size_t)(N_NODES + 1) * 4);
  int*   fill    = (int*)alloc((size_t)N_NODES * 4);
  int2*  srcperm = (int2*)alloc((size_t)ETOT * 8);
  unsigned short* attr_bf = (unsigned short*)alloc((size_t)N_EDGES * FE * 2);
  float* partial = (float*)alloc((size_t)MEAN_BLOCKS * HID * 4);
  float* meanv   = (float*)alloc(HID * 4);
  float* e_self  = (float*)alloc(HID * 4);
  float* xh      = (float*)alloc((size_t)N_NODES * HID * 4);
  float* xl      = (float*)alloc((size_t)N_NODES * HID * 4);
  float* xr      = (float*)alloc((size_t)N_NODES * HID * 4);
  float* xo      = xh;   // alias: xh is dead between k_xlr and k_bnapply

  hipMemsetAsync(d_ws, 0, zero_bytes, stream);

  k_node_embed<<<N_NODES / 4, 256, 0, stream>>>(x, node_W, node_b, xh);
  k_hist<<<1024, 256, 0, stream>>>(ei, counts);
  k_scan<<<1, 1024, 0, stream>>>(counts, row_ptr, fill);
  k_scatter<<<1024, 256, 0, stream>>>(ei, fill, srcperm);
  k_attr_cvt<<<N_EDGES * FE / 4 / 256, 256, 0, stream>>>(eattr, attr_bf);
  k_meanp<<<MEAN_BLOCKS, 256, 0, stream>>>(eattr, eemb_W, eemb_b, partial);
  k_mean<<<1, 256, 0, stream>>>(partial, meanv);

  const int ablocks = (N_NODES + 3) / 4;
  for (int L = 0; L < 3; ++L) {
    const float* Wl  = (const float*)d_in[8 + 9 * L + 0];
    const float* bl  = (const float*)d_in[8 + 9 * L + 1];
    const float* Wr  = (const float*)d_in[8 + 9 * L + 2];
    const float* br  = (const float*)d_in[8 + 9 * L + 3];
    const float* Wed = (const float*)d_in[8 + 9 * L + 4];
    const float* att = (const float*)d_in[8 + 9 * L + 5];
    const float* cb  = (const float*)d_in[8 + 9 * L + 6];
    const float* g   = (const float*)d_in[8 + 9 * L + 7];
    const float* bt  = (const float*)d_in[8 + 9 * L + 8];
    k_xlr<<<N_NODES / 4, 256, 0, stream>>>(xh, Wl, bl, Wr, br, xl, xr);
    k_eself<<<1, 64, 0, stream>>>(meanv, Wed, e_self);
    if (L < 2)
      k_attn_f<16><<<ablocks, 256, 0, stream>>>(xl, xr, attr_bf, srcperm, row_ptr,
                                                eemb_W, eemb_b, Wed, e_self, att, cb, xo);
    else
      k_attn_f<64><<<ablocks, 256, 0, stream>>>(xl, xr, attr_bf, srcperm, row_ptr,
                                                eemb_W, eemb_b, Wed, e_self, att, cb, xo);
    k_bnstats<<<256, 256, 0, stream>>>(xo, bns + L * 128);
    k_bnapply<<<N_NODES * HID / 256, 256, 0, stream>>>(xo, bns + L * 128, g, bt, xh);
  }

  k_pool<<<64, 256, 0, stream>>>(xh, batch, pooled);
  k_readout<<<1, 256, 0, stream>>>(pooled, ro1_W, ro1_b, ro2_W, ro2_b, out);
}

// Round 6
// 1628.603 us; speedup vs baseline: 1.3049x; 1.0375x over previous
//
#include <hip/hip_runtime.h>
#include <stdint.h>

#define N_NODES 50000
#define N_EDGES 1600000
#define ETOT    (N_EDGES + N_NODES)
#define FN 16
#define FE 8
#define HID 64
#define NGR 8
#define NEG_ATT 0.2f
#define NEG_ACT 0.01f
#define EPS_BN 1e-5f
#define MEAN_BLOCKS 512
#define SELF_FLAG 0x40000000
#define SRC_MASK  0x3FFFFFFF
#define SCAN_BLOCKS 196   // ceil(50000/256)

typedef __attribute__((ext_vector_type(8))) short short8;
typedef __attribute__((ext_vector_type(4))) float f32x4;

__device__ __forceinline__ float bf2f(unsigned short u) {
  union { unsigned int i; float f; } c; c.i = ((unsigned int)u) << 16; return c.f;
}
__device__ __forceinline__ unsigned short f2bf(float f) {
  union { float f; unsigned int i; } c; c.f = f;
  unsigned int r = c.i + 0x7FFFu + ((c.i >> 16) & 1u);
  return (unsigned short)(r >> 16);
}
__device__ __forceinline__ float lrelu(float x, float s) { return x > 0.f ? x : s * x; }

// ---------------- K1: xh = x @ node_W + node_b ----------------
__global__ __launch_bounds__(256) void k_node_embed(
    const float* __restrict__ x, const float* __restrict__ W,
    const float* __restrict__ b, float* __restrict__ xh) {
  __shared__ float sW[FN * HID];
  int t = threadIdx.x;
  for (int i = t; i < FN * HID; i += 256) sW[i] = W[i];
  __syncthreads();
  int j = t & 63;
  int v = blockIdx.x * 4 + (t >> 6);
  const float* xr = x + v * FN;
  float acc = b[j];
#pragma unroll
  for (int k = 0; k < FN; ++k) acc += xr[k] * sW[k * HID + j];
  xh[v * HID + j] = acc;
}

// ---------------- K2: in-degree histogram over dst ----------------
__global__ __launch_bounds__(256) void k_hist(const int* __restrict__ ei,
                                              int* __restrict__ counts) {
  int i = blockIdx.x * blockDim.x + threadIdx.x;
  int stride = gridDim.x * blockDim.x;
  for (; i < N_EDGES; i += stride) atomicAdd(&counts[ei[N_EDGES + i]], 1);
}

// ---------------- K3: 3-phase parallel exclusive scan ----------------
__global__ __launch_bounds__(256) void k_scanA(const int* __restrict__ counts,
                                               int* __restrict__ row_ptr,
                                               int* __restrict__ blocksum) {
  __shared__ int s[256];
  int t = threadIdx.x;
  int v = blockIdx.x * 256 + t;
  int val = (v < N_NODES) ? counts[v] + 1 : 0;   // +1 self loop
  s[t] = val; __syncthreads();
  for (int off = 1; off < 256; off <<= 1) {
    int add = (t >= off) ? s[t - off] : 0;
    __syncthreads();
    s[t] += add;
    __syncthreads();
  }
  if (v < N_NODES) row_ptr[v] = s[t] - val;      // block-local exclusive
  if (t == 255) blocksum[blockIdx.x] = s[255];
}

__global__ __launch_bounds__(256) void k_scanB(const int* __restrict__ blocksum,
                                               int* __restrict__ blockoff,
                                               int* __restrict__ row_ptr) {
  __shared__ int s[256];
  int t = threadIdx.x;
  int val = (t < SCAN_BLOCKS) ? blocksum[t] : 0;
  s[t] = val; __syncthreads();
  for (int off = 1; off < 256; off <<= 1) {
    int add = (t >= off) ? s[t - off] : 0;
    __syncthreads();
    s[t] += add;
    __syncthreads();
  }
  if (t < SCAN_BLOCKS) blockoff[t] = s[t] - val;
  if (t == 255) row_ptr[N_NODES] = s[255];
}

__global__ __launch_bounds__(256) void k_scanC(int* __restrict__ row_ptr,
                                               int* __restrict__ fill,
                                               const int* __restrict__ blockoff) {
  int t = threadIdx.x;
  int v = blockIdx.x * 256 + t;
  if (v < N_NODES) {
    int rp = row_ptr[v] + blockoff[blockIdx.x];
    row_ptr[v] = rp;
    fill[v] = rp;
  }
}

// ------- K4: scatter (src|flag, perm) 8B records, dst-sorted -------
__global__ __launch_bounds__(256) void k_scatter(const int* __restrict__ ei,
                                                 int* __restrict__ fill,
                                                 int2* __restrict__ srcperm) {
  int i = blockIdx.x * blockDim.x + threadIdx.x;
  int stride = gridDim.x * blockDim.x;
  for (; i < ETOT; i += stride) {
    if (i < N_EDGES) {
      int d = ei[N_EDGES + i];
      int pos = atomicAdd(&fill[d], 1);
      srcperm[pos] = make_int2(ei[i], i);
    } else {
      int v = i - N_EDGES;
      int pos = atomicAdd(&fill[v], 1);
      srcperm[pos] = make_int2(v | SELF_FLAG, 0);
    }
  }
}

// ------- K4b: edge_attr fp32 -> bf16, original order (coalesced) -------
__global__ __launch_bounds__(256) void k_attr_cvt(const float* __restrict__ eattr,
                                                  unsigned short* __restrict__ attr_bf) {
  int idx = blockIdx.x * 256 + threadIdx.x;   // over N_EDGES*FE/4
  float4 a = ((const float4*)eattr)[idx];
  unsigned int lo = (unsigned int)f2bf(a.x) | ((unsigned int)f2bf(a.y) << 16);
  unsigned int hi = (unsigned int)f2bf(a.z) | ((unsigned int)f2bf(a.w) << 16);
  ((int2*)attr_bf)[idx] = make_int2((int)lo, (int)hi);
}

// ------- K5: mean of ea over real edges — LDS-staged, coalesced -------
__global__ __launch_bounds__(256) void k_meanp(const float* __restrict__ eattr,
                                               const float* __restrict__ eW,
                                               const float* __restrict__ eb,
                                               float* __restrict__ partial) {
  __shared__ float sA[256 * FE];
  __shared__ float sred[256];
  int t = threadIdx.x; int j = t & 63; int w = t >> 6;
  float Wj[8];
#pragma unroll
  for (int k = 0; k < 8; ++k) Wj[k] = eW[k * HID + j];
  float bj = eb[j], msum = 0.f;
  const int TILES = N_EDGES / 256;
  for (int tile = blockIdx.x; tile < TILES; tile += gridDim.x) {
    __syncthreads();
    const float4* src = (const float4*)(eattr + (size_t)tile * 256 * FE);
    ((float4*)sA)[t] = src[t];
    ((float4*)sA)[t + 256] = src[t + 256];
    __syncthreads();
#pragma unroll 8
    for (int e = 0; e < 64; ++e) {
      const float4* ar = (const float4*)(sA + (w * 64 + e) * FE);
      float4 A0 = ar[0], A1 = ar[1];
      float acc = bj + A0.x * Wj[0] + A0.y * Wj[1] + A0.z * Wj[2] + A0.w * Wj[3]
                     + A1.x * Wj[4] + A1.y * Wj[5] + A1.z * Wj[6] + A1.w * Wj[7];
      msum += lrelu(acc, NEG_ACT);
    }
  }
  sred[t] = msum; __syncthreads();
  if (w == 0)
    partial[blockIdx.x * HID + j] = sred[j] + sred[j + 64] + sred[j + 128] + sred[j + 192];
}

__global__ __launch_bounds__(256) void k_mean(const float* __restrict__ partial,
                                              float* __restrict__ mean) {
  __shared__ float sred[256];
  int t = threadIdx.x; int j = t & 63; int w = t >> 6;
  float s = 0.f;
  for (int bk = w; bk < MEAN_BLOCKS; bk += 4) s += partial[bk * HID + j];
  sred[t] = s; __syncthreads();
  if (w == 0)
    mean[j] = (sred[j] + sred[j + 64] + sred[j + 128] + sred[j + 192]) / (float)N_EDGES;
}

// ------- K6: e_self = mean(ea) @ Wed (fp32 exact) -------
__global__ void k_eself(const float* __restrict__ meanv,
                        const float* __restrict__ Wed,
                        float* __restrict__ e_self) {
  int j = threadIdx.x;
  float s = 0.f;
  for (int k = 0; k < HID; ++k) s += meanv[k] * Wed[k * HID + j];
  e_self[j] = s;
}

// ------- K7: xl(bf16) = xh@Wl+bl, xr(f32) = xh@Wr+br -------
__global__ __launch_bounds__(256) void k_xlr(const float* __restrict__ xh,
                                             const float* __restrict__ Wl,
                                             const float* __restrict__ bl,
                                             const float* __restrict__ Wr,
                                             const float* __restrict__ br,
                                             unsigned short* __restrict__ xl_bf,
                                             float* __restrict__ xr) {
  __shared__ float sWl[HID * HID], sWr[HID * HID];
  __shared__ float srow[4][HID];
  int t = threadIdx.x;
  for (int i = t; i < HID * HID; i += 256) { sWl[i] = Wl[i]; sWr[i] = Wr[i]; }
  __syncthreads();
  int j = t & 63; int w = t >> 6;
  int v = blockIdx.x * 4 + w;
  srow[w][j] = xh[v * HID + j];
  __syncthreads();
  float accL = bl[j], accR = br[j];
#pragma unroll
  for (int k = 0; k < HID; ++k) {
    float xk = srow[w][k];
    accL += xk * sWl[k * HID + j];
    accR += xk * sWr[k * HID + j];
  }
  xl_bf[v * HID + j] = f2bf(accL);
  xr[v * HID + j] = accR;
}

// ======= K8: FUSED attention, static 16-edge tiles, batched gathers =======
template <int HW>
__global__ __launch_bounds__(256) void k_attn_f(
    const unsigned short* __restrict__ xl_bf, const float* __restrict__ xr,
    const unsigned short* __restrict__ attr_bf,
    const int2* __restrict__ srcperm, const int* __restrict__ row_ptr,
    const float* __restrict__ eW, const float* __restrict__ eb,
    const float* __restrict__ Wed, const float* __restrict__ e_self,
    const float* __restrict__ att, const float* __restrict__ cb,
    float* __restrict__ xo) {
  // LDS union: T1 persistent (9216 B); preamble {sWed,sEw,sEb} aliases T2 (main loop)
  __shared__ __align__(16) char smem[9216 + 16896];
  unsigned short* T1   = (unsigned short*)smem;                 // [4][16][72] bf16
  unsigned short* sWed = (unsigned short*)(smem + 9216);        // [64*64] bf16
  unsigned short* sEw  = (unsigned short*)(smem + 9216 + 8192); // [8*64] bf16
  float*          sEb  = (float*)(smem + 9216 + 8192 + 1024);   // [64]
  float*          T2   = (float*)(smem + 9216);                 // [4][16][66] f32

  int t = threadIdx.x;
  for (int i = t; i < HID * HID; i += 256) sWed[i] = f2bf(Wed[i]);
  for (int i = t; i < FE * HID; i += 256) sEw[i] = f2bf(eW[i]);
  if (t < HID) sEb[t] = eb[t];
  __syncthreads();

  int lane = t & 63, w = t >> 6, l15 = lane & 15, lg = lane >> 4;

  // Wed B-frags: B[k][col], col=l15(+16jc), k=8lg+i (+32 for kh=1)
  short8 bW[4][2];
#pragma unroll
  for (int jc = 0; jc < 4; ++jc)
#pragma unroll
    for (int kh = 0; kh < 2; ++kh)
#pragma unroll
      for (int i = 0; i < 8; ++i)
        bW[jc][kh][i] = (short)sWed[(8 * lg + i + 32 * kh) * HID + jc * 16 + l15];
  // eW B-frags (K padded 8->32: only lg==0 holds real k=0..7)
  short8 bE[4] = {};
  if (lg == 0)
#pragma unroll
    for (int jc = 0; jc < 4; ++jc)
#pragma unroll
      for (int i = 0; i < 8; ++i)
        bE[jc][i] = (short)sEw[i * HID + jc * 16 + l15];
  float biasv[4];
#pragma unroll
  for (int jc = 0; jc < 4; ++jc) biasv[jc] = sEb[jc * 16 + l15];
  __syncthreads();   // all waves done reading sWed/sEw/sEb before T2 overwrites

  int v = blockIdx.x * 4 + w;
  if (v >= N_NODES) return;

  float xrv = xr[v * HID + lane];
  float attj = att[lane];
  float esj = e_self[lane];
  float cbj = cb[lane];
  int beg = row_ptr[v], end = row_ptr[v + 1];
  float M = -3.0e38f, S = 0.f, acc = 0.f;

  unsigned short* T1w = T1 + w * 16 * 72;
  float* T2w = T2 + w * 16 * 66;

  for (int base = beg; base < end; base += 16) {
    int cnt = end - base; if (cnt > 16) cnt = 16;
    int eidx = base + l15; if (eidx >= end) eidx = end - 1;
    int2 sp = srcperm[eidx];

    // ---- batched gathers: xls[i] for all 16 tile edges (16-deep MLP)
    float xls[16];
#pragma unroll
    for (int i = 0; i < 16; ++i) {
      int raw = __builtin_amdgcn_readlane(sp.x, i);       // scalar broadcast
      unsigned srcv = (unsigned)(raw & SRC_MASK);
      xls[i] = bf2f(xl_bf[srcv * 64u + (unsigned)lane]);  // coalesced 128B row
    }

    // ---- MFMA1: ea = attr(16x8, K-pad 32) @ eW -> D[edge=4lg+i][ch=jc16+l15]
    short8 a0 = {};
    if (lg == 0 && !(sp.x & SELF_FLAG))
      a0 = *(const short8*)(attr_bf + (size_t)sp.y * FE);
    f32x4 accE[4];
#pragma unroll
    for (int jc = 0; jc < 4; ++jc) {
      f32x4 z = {};
      accE[jc] = __builtin_amdgcn_mfma_f32_16x16x32_bf16(a0, bE[jc], z, 0, 0, 0);
    }
#pragma unroll
    for (int jc = 0; jc < 4; ++jc)
#pragma unroll
      for (int i = 0; i < 4; ++i)
        T1w[(4 * lg + i) * 72 + jc * 16 + l15] =
            f2bf(lrelu(accE[jc][i] + biasv[jc], NEG_ACT));
    __builtin_amdgcn_wave_barrier();
    asm volatile("s_waitcnt lgkmcnt(0)" ::: "memory");
    __builtin_amdgcn_sched_barrier(0);

    // ---- MFMA2: e = ea(16x64) @ Wed -> T2[edge][ch]
    short8 A0 = *(const short8*)&T1w[l15 * 72 + 8 * lg];
    short8 A1 = *(const short8*)&T1w[l15 * 72 + 32 + 8 * lg];
    f32x4 acc2[4];
#pragma unroll
    for (int jc = 0; jc < 4; ++jc) {
      f32x4 z = {};
      acc2[jc] = __builtin_amdgcn_mfma_f32_16x16x32_bf16(A0, bW[jc][0], z, 0, 0, 0);
      acc2[jc] = __builtin_amdgcn_mfma_f32_16x16x32_bf16(A1, bW[jc][1], acc2[jc], 0, 0, 0);
    }
#pragma unroll
    for (int jc = 0; jc < 4; ++jc)
#pragma unroll
      for (int i = 0; i < 4; ++i)
        T2w[(4 * lg + i) * 66 + jc * 16 + l15] = acc2[jc][i];
    __builtin_amdgcn_wave_barrier();
    asm volatile("s_waitcnt lgkmcnt(0)" ::: "memory");
    __builtin_amdgcn_sched_barrier(0);

    // ---- scores (16 independent butterflies), tail masked to -inf
    float r[16];
#pragma unroll
    for (int i = 0; i < 16; ++i) {
      int raw = __builtin_amdgcn_readlane(sp.x, i);
      float e = (raw & SELF_FLAG) ? esj : T2w[i * 66 + lane];
      float mm = lrelu(xls[i] + xrv + e, NEG_ATT) * attj;
#pragma unroll
      for (int o = 1; o < HW; o <<= 1) mm += __shfl_xor(mm, o, 64);
      r[i] = (i < cnt) ? mm : -3.0e38f;
    }
    // ---- single 16-way online-softmax merge
    float mx = r[0];
#pragma unroll
    for (int i = 1; i < 16; ++i) mx = fmaxf(mx, r[i]);
    float Mn = fmaxf(M, mx);
    float sc = __expf(M - Mn);
    acc *= sc; S *= sc;
#pragma unroll
    for (int i = 0; i < 16; ++i) {
      float wi = __expf(r[i] - Mn);
      S += wi;
      acc += wi * xls[i];
    }
    M = Mn;
    __builtin_amdgcn_wave_barrier();
  }
  xo[v * HID + lane] = acc / S + cbj;
}

// ---------------- K10: BN stats ----------------
__global__ __launch_bounds__(256) void k_bnstats(const float* __restrict__ xo,
                                                 float* __restrict__ bns) {
  __shared__ float s1[256], s2[256];
  int t = threadIdx.x; int j = t & 63; int r = t >> 6;
  float sum = 0.f, sq = 0.f;
  int stride = gridDim.x * 4;
  for (int v = blockIdx.x * 4 + r; v < N_NODES; v += stride) {
    float x = xo[v * HID + j];
    sum += x; sq += x * x;
  }
  s1[t] = sum; s2[t] = sq; __syncthreads();
  if (r == 0) {
    atomicAdd(&bns[j], s1[j] + s1[j + 64] + s1[j + 128] + s1[j + 192]);
    atomicAdd(&bns[64 + j], s2[j] + s2[j + 64] + s2[j + 128] + s2[j + 192]);
  }
}

// ---------------- K11: BN apply + LeakyReLU (in-place safe) ----------------
__global__ __launch_bounds__(256) void k_bnapply(const float* __restrict__ xo,
                                                 const float* __restrict__ bns,
                                                 const float* __restrict__ g,
                                                 const float* __restrict__ b,
                                                 float* __restrict__ xh) {
  int tid = blockIdx.x * 256 + threadIdx.x;
  int j = tid & 63;
  int v = tid >> 6;
  if (v >= N_NODES) return;
  const float invN = 1.f / (float)N_NODES;
  float mu = bns[j] * invN;
  float var = bns[64 + j] * invN - mu * mu;
  var = fmaxf(var, 0.f);
  float y = (xo[v * HID + j] - mu) * rsqrtf(var + EPS_BN) * g[j] + b[j];
  xh[v * HID + j] = lrelu(y, NEG_ACT);
}

// ---------------- K12: global add pool ----------------
__global__ __launch_bounds__(256) void k_pool(const float* __restrict__ xh,
                                              const int* __restrict__ batch,
                                              float* __restrict__ pooled) {
  __shared__ float lacc[4][NGR][HID];
  int t = threadIdx.x; int j = t & 63; int r = t >> 6;
  float a[NGR];
#pragma unroll
  for (int gg = 0; gg < NGR; ++gg) a[gg] = 0.f;
  int stride = gridDim.x * 4;
  for (int v = blockIdx.x * 4 + r; v < N_NODES; v += stride) {
    int g = batch[v];
    float x = xh[v * HID + j];
#pragma unroll
    for (int gg = 0; gg < NGR; ++gg) a[gg] += (g == gg) ? x : 0.f;
  }
#pragma unroll
  for (int gg = 0; gg < NGR; ++gg) lacc[r][gg][j] = a[gg];
  __syncthreads();
  if (r == 0) {
#pragma unroll
    for (int gg = 0; gg < NGR; ++gg)
      atomicAdd(&pooled[gg * HID + j],
                lacc[0][gg][j] + lacc[1][gg][j] + lacc[2][gg][j] + lacc[3][gg][j]);
  }
}

// ---------------- K13: readout ----------------
__global__ __launch_bounds__(256) void k_readout(const float* __restrict__ pooled,
                                                 const float* __restrict__ W1,
                                                 const float* __restrict__ b1,
                                                 const float* __restrict__ W2,
                                                 const float* __restrict__ b2,
                                                 float* __restrict__ out) {
  __shared__ float hid[NGR][32];
  int t = threadIdx.x;
  int g = t >> 5, q = t & 31;
  float acc = b1[q];
  for (int k = 0; k < HID; ++k) acc += pooled[g * HID + k] * W1[k * 32 + q];
  hid[g][q] = lrelu(acc, NEG_ACT);
  __syncthreads();
  if (t < NGR) {
    float o = b2[0];
    for (int q2 = 0; q2 < 32; ++q2) o += hid[t][q2] * W2[q2];
    out[t] = o;
  }
}

extern "C" void kernel_launch(void* const* d_in, const int* in_sizes, int n_in,
                              void* d_out, int out_size, void* d_ws, size_t ws_size,
                              hipStream_t stream) {
  (void)in_sizes; (void)n_in; (void)out_size; (void)ws_size;
  const float* x      = (const float*)d_in[0];
  const int*   ei     = (const int*)d_in[1];
  const float* eattr  = (const float*)d_in[2];
  const int*   batch  = (const int*)d_in[3];
  const float* node_W = (const float*)d_in[4];
  const float* node_b = (const float*)d_in[5];
  const float* eemb_W = (const float*)d_in[6];
  const float* eemb_b = (const float*)d_in[7];
  const float* ro1_W  = (const float*)d_in[35];
  const float* ro1_b  = (const float*)d_in[36];
  const float* ro2_W  = (const float*)d_in[37];
  const float* ro2_b  = (const float*)d_in[38];
  float* out = (float*)d_out;

  char* p = (char*)d_ws;
  auto alloc = [&](size_t bytes) {
    char* r = p;
    p += (bytes + 255) & ~(size_t)255;
    return r;
  };
  // --- zero zone (single memset) ---
  int*   counts = (int*)alloc((size_t)N_NODES * 4);
  float* bns    = (float*)alloc(3 * 128 * 4);
  float* pooled = (float*)alloc(NGR * HID * 4);
  size_t zero_bytes = (size_t)(p - (char*)d_ws);
  // --- fixed buffers (each written before read every call) ---
  int*   row_ptr  = (int*)alloc((size_t)(N_NODES + 1) * 4);
  int*   fill     = (int*)alloc((size_t)N_NODES * 4);
  int*   blocksum = (int*)alloc((size_t)SCAN_BLOCKS * 4);
  int*   blockoff = (int*)alloc((size_t)SCAN_BLOCKS * 4);
  int2*  srcperm  = (int2*)alloc((size_t)ETOT * 8);
  unsigned short* attr_bf = (unsigned short*)alloc((size_t)N_EDGES * FE * 2);
  float* partial = (float*)alloc((size_t)MEAN_BLOCKS * HID * 4);
  float* meanv   = (float*)alloc(HID * 4);
  float* e_self  = (float*)alloc(HID * 4);
  float* xh      = (float*)alloc((size_t)N_NODES * HID * 4);
  unsigned short* xl_bf = (unsigned short*)alloc((size_t)N_NODES * HID * 2);
  float* xr      = (float*)alloc((size_t)N_NODES * HID * 4);
  float* xo      = xh;   // alias: xh is dead between k_xlr and k_bnapply

  hipMemsetAsync(d_ws, 0, zero_bytes, stream);

  k_node_embed<<<N_NODES / 4, 256, 0, stream>>>(x, node_W, node_b, xh);
  k_hist<<<1024, 256, 0, stream>>>(ei, counts);
  k_scanA<<<SCAN_BLOCKS, 256, 0, stream>>>(counts, row_ptr, blocksum);
  k_scanB<<<1, 256, 0, stream>>>(blocksum, blockoff, row_ptr);
  k_scanC<<<SCAN_BLOCKS, 256, 0, stream>>>(row_ptr, fill, blockoff);
  k_scatter<<<1024, 256, 0, stream>>>(ei, fill, srcperm);
  k_attr_cvt<<<N_EDGES * FE / 4 / 256, 256, 0, stream>>>(eattr, attr_bf);
  k_meanp<<<MEAN_BLOCKS, 256, 0, stream>>>(eattr, eemb_W, eemb_b, partial);
  k_mean<<<1, 256, 0, stream>>>(partial, meanv);

  const int ablocks = (N_NODES + 3) / 4;
  for (int L = 0; L < 3; ++L) {
    const float* Wl  = (const float*)d_in[8 + 9 * L + 0];
    const float* bl  = (const float*)d_in[8 + 9 * L + 1];
    const float* Wr  = (const float*)d_in[8 + 9 * L + 2];
    const float* br  = (const float*)d_in[8 + 9 * L + 3];
    const float* Wed = (const float*)d_in[8 + 9 * L + 4];
    const float* att = (const float*)d_in[8 + 9 * L + 5];
    const float* cb  = (const float*)d_in[8 + 9 * L + 6];
    const float* g   = (const float*)d_in[8 + 9 * L + 7];
    const float* bt  = (const float*)d_in[8 + 9 * L + 8];
    k_xlr<<<N_NODES / 4, 256, 0, stream>>>(xh, Wl, bl, Wr, br, xl_bf, xr);
    k_eself<<<1, 64, 0, stream>>>(meanv, Wed, e_self);
    if (L < 2)
      k_attn_f<16><<<ablocks, 256, 0, stream>>>(xl_bf, xr, attr_bf, srcperm, row_ptr,
                                                eemb_W, eemb_b, Wed, e_self, att, cb, xo);
    else
      k_attn_f<64><<<ablocks, 256, 0, stream>>>(xl_bf, xr, attr_bf, srcperm, row_ptr,
                                                eemb_W, eemb_b, Wed, e_self, att, cb, xo);
    k_bnstats<<<256, 256, 0, stream>>>(xo, bns + L * 128);
    k_bnapply<<<N_NODES * HID / 256, 256, 0, stream>>>(xo, bns + L * 128, g, bt, xh);
  }

  k_pool<<<64, 256, 0, stream>>>(xh, batch, pooled);
  k_readout<<<1, 256, 0, stream>>>(pooled, ro1_W, ro1_b, ro2_W, ro2_b, out);
}